// Round 14
// baseline (120.644 us; speedup 1.0000x reference)
//
#include <hip/hip_runtime.h>
#include <math.h>

#define IN_DIM 256
#define HD 256
#define EDGE_DIM 32
#define NEG_SLOPE 0.2f
#define NTHR 256
#define WCVT_VBS 32
#define NB 128         // histogram chunks (one block/CU)
#define LDSW 10016     // packed u16 counter words; supports n <= 20032

typedef _Float16 f16x8 __attribute__((ext_vector_type(8)));
typedef _Float16 f16x4 __attribute__((ext_vector_type(4)));
typedef float f32x4 __attribute__((ext_vector_type(4)));

__device__ __forceinline__ f16x8 cvt8(const float* p) {
    float4 lo = *(const float4*)p;
    float4 hi = *(const float4*)(p + 4);
    auto a = __builtin_amdgcn_cvt_pkrtz(lo.x, lo.y);
    auto b = __builtin_amdgcn_cvt_pkrtz(lo.z, lo.w);
    auto c = __builtin_amdgcn_cvt_pkrtz(hi.x, hi.y);
    auto d = __builtin_amdgcn_cvt_pkrtz(hi.z, hi.w);
    f16x8 r;
    r[0] = (_Float16)a[0]; r[1] = (_Float16)a[1];
    r[2] = (_Float16)b[0]; r[3] = (_Float16)b[1];
    r[4] = (_Float16)c[0]; r[5] = (_Float16)c[1];
    r[6] = (_Float16)d[0]; r[7] = (_Float16)d[1];
    return r;
}

// per-block int64-vs-int32 detect: high words of int64 node ids are all zero
__device__ __forceinline__ int detect64(const int* __restrict__ ei) {
    __shared__ int anynz;
    if (threadIdx.x == 0) anynz = 0;
    __syncthreads();
    if (ei[2 * threadIdx.x + 1] != 0) atomicOr(&anynz, 1);
    __syncthreads();
    return anynz == 0;
}

__device__ __forceinline__ void load_edge(const int* ei, int e, int E, int n, int is64,
                                          int& s, int& d) {
    if (e < E) {
        if (is64) { s = ei[2 * e]; d = ei[2 * E + 2 * e]; }
        else      { s = ei[e];     d = ei[E + e]; }
    } else {
        s = d = e - E;  // self loop
    }
}

// ---------- k_pre: weff (b0) | W->fp16 k-major repack (b1..32) | zero deg (b33..) ----------
// Whr layout: [k/8][col][8] f16 -> proj's B-fragment load is 256B contiguous per wave.
__global__ __launch_bounds__(NTHR) void k_pre(const float* __restrict__ lew,
                                              const float* __restrict__ ae,
                                              const float* __restrict__ W,
                                              float* __restrict__ weff,
                                              _Float16* __restrict__ Whr,
                                              int* __restrict__ deg, int n4) {
    int b = blockIdx.x;
    int t = threadIdx.x;
    if (b == 0) {
        if (t < 128) {
            int h = t >> 5, k = t & 31;
            float s = 0.f;
#pragma unroll 8
            for (int d = 0; d < 64; ++d) s += lew[(h * 64 + d) * 32 + k] * ae[h * 64 + d];
            weff[t] = s;
        }
    } else if (b <= WCVT_VBS) {
        int idx = (b - 1) * 2048 + t * 8;   // element index into row-major W (col*256+k)
        int col = idx >> 8;
        int k = idx & 255;                  // 8 consecutive k
        f16x8 v = cvt8(&W[idx]);
        *(f16x8*)&Whr[(size_t)(k >> 3) * 2048 + col * 8] = v;
    } else {
        int i = (b - 1 - WCVT_VBS) * 1024 + t * 4;
        if (i < n4) *(int4*)&deg[i] = make_int4(0, 0, 0, 0);
    }
}

// ---------- k_hist_lds: per-chunk LDS histogram (packed u16) + perm ----------
// perm[e] = within-(chunk, node) ordinal. cnt_g[b][w] = packed per-chunk counts.
__global__ __launch_bounds__(NTHR) void k_hist_lds(const int* __restrict__ ei,
                                                   int* __restrict__ cnt_g,
                                                   int* __restrict__ perm,
                                                   int chunk, int E, int n) {
    __shared__ int cnt_l[LDSW];
    int b = blockIdx.x;
    int t = threadIdx.x;
    int is64 = detect64(ei);
    int nw = (n + 1) >> 1;
    for (int i = t; i < nw; i += NTHR) cnt_l[i] = 0;
    __syncthreads();
    int e0 = b * chunk;
    int e1 = e0 + chunk;
    if (e1 > E) e1 = E;
    for (int e = e0 + t; e < e1; e += NTHR) {
        int d = is64 ? ei[2 * E + 2 * e] : ei[E + e];
        int sh = (d & 1) * 16;
        int old = atomicAdd(&cnt_l[d >> 1], 1 << sh);
        perm[e] = (old >> sh) & 0xffff;
    }
    __syncthreads();
    for (int i = t; i < nw; i += NTHR) cnt_g[(size_t)b * nw + i] = cnt_l[i];
}

// ---------- k_h2: cross-chunk exclusive prefix -> off_g[b][node], deg[node] ----------
__global__ __launch_bounds__(NTHR) void k_h2(const int* __restrict__ cnt_g,
                                             int* __restrict__ off_g,
                                             int* __restrict__ deg, int n) {
    int nw = (n + 1) >> 1;
    int w = blockIdx.x * NTHR + threadIdx.x;
    if (w >= nw) return;
    int r0 = 0, r1 = 0;
    for (int b = 0; b < NB; ++b) {
        int v = cnt_g[(size_t)b * nw + w];
        off_g[(size_t)b * n + 2 * w] = r0;
        if (2 * w + 1 < n) off_g[(size_t)b * n + 2 * w + 1] = r1;
        r0 += v & 0xffff;
        r1 += (v >> 16) & 0xffff;
    }
    deg[2 * w] = r0;
    if (2 * w + 1 < n) deg[2 * w + 1] = r1;
}

// ---------- fallback: global-atomic histogram (n > 2*LDSW) ----------
__global__ __launch_bounds__(NTHR) void k_hist_glb(const int* __restrict__ ei,
                                                   int* __restrict__ deg,
                                                   int* __restrict__ perm, int E) {
    int is64 = detect64(ei);
    int e0 = (blockIdx.x * NTHR + threadIdx.x) * 4;
    if (e0 >= E) return;
    for (int e = e0; e < E && e < e0 + 4; ++e) {
        int d = is64 ? ei[2 * E + 2 * e] : ei[E + e];
        perm[e] = atomicAdd(&deg[d], 1);
    }
}

// ---------- k_proj: 32 rows/block; x staged in LDS (f16, k-major planes); Whr coalesced ----
#define XPLN 33
__global__ __launch_bounds__(NTHR) void k_proj(const float* __restrict__ x,
                                               const _Float16* __restrict__ Whr,
                                               const float* __restrict__ asrc_g,
                                               const float* __restrict__ adst_g,
                                               _Float16* __restrict__ xph,
                                               float* __restrict__ s_src,
                                               float* __restrict__ s_dst, int n) {
    __shared__ _Float16 xs[32 * XPLN * 8];   // 16.9 KB
    int t = threadIdx.x;
    int lane = t & 63;
    int w = t >> 6;              // wave id == head id (col group)
    int m0 = blockIdx.x * 32;
    int c0 = w * 64;
    int r = lane & 15;
    int kq = lane >> 4;          // 0..3

    // ---- stage 32 x-rows -> LDS f16 (coalesced 128B per thread) ----
    {
        int rr = t >> 3;               // 0..31
        int kc = (t & 7) * 32;         // 0..224
        int grow = m0 + rr;
        if (grow < n) {
            const float* xp = &x[(size_t)grow * IN_DIM + kc];
#pragma unroll
            for (int c4 = 0; c4 < 4; ++c4) {
                f16x8 v = cvt8(xp + c4 * 8);
                *(f16x8*)&xs[(size_t)((kc >> 3) + c4) * (XPLN * 8) + rr * 8] = v;
            }
        } else {
            f16x8 z = {0, 0, 0, 0, 0, 0, 0, 0};
#pragma unroll
            for (int c4 = 0; c4 < 4; ++c4)
                *(f16x8*)&xs[(size_t)((kc >> 3) + c4) * (XPLN * 8) + rr * 8] = z;
        }
    }

    float asr[4], ads[4];
#pragma unroll
    for (int ci = 0; ci < 4; ++ci) {
        asr[ci] = asrc_g[c0 + ci * 16 + r];
        ads[ci] = adst_g[c0 + ci * 16 + r];
    }

    f32x4 acc[2][4];
#pragma unroll
    for (int mi = 0; mi < 2; ++mi)
#pragma unroll
        for (int j = 0; j < 4; ++j) acc[mi][j] = (f32x4){0.f, 0.f, 0.f, 0.f};

    __syncthreads();

#pragma unroll
    for (int k0 = 0; k0 < IN_DIM; k0 += 32) {
        int p = (k0 >> 3) + kq;
        f16x8 a0 = *(const f16x8*)&xs[(size_t)p * (XPLN * 8) + (0 * 16 + r) * 8];
        f16x8 a1 = *(const f16x8*)&xs[(size_t)p * (XPLN * 8) + (1 * 16 + r) * 8];
        f16x8 bfr[4];
#pragma unroll
        for (int ci = 0; ci < 4; ++ci)
            bfr[ci] = *(const f16x8*)&Whr[(size_t)p * 2048 + (c0 + ci * 16 + r) * 8];
#pragma unroll
        for (int ci = 0; ci < 4; ++ci) {
            acc[0][ci] = __builtin_amdgcn_mfma_f32_16x16x32_f16(a0, bfr[ci], acc[0][ci],
                                                                0, 0, 0);
            acc[1][ci] = __builtin_amdgcn_mfma_f32_16x16x32_f16(a1, bfr[ci], acc[1][ci],
                                                                0, 0, 0);
        }
    }
    // C/D layout: col = lane&15, row = (lane>>4)*4 + j
#pragma unroll
    for (int mi = 0; mi < 2; ++mi) {
#pragma unroll
        for (int j = 0; j < 4; ++j) {
            int orow = m0 + mi * 16 + kq * 4 + j;
            if (orow < n) {
#pragma unroll
                for (int ci = 0; ci < 4; ++ci)
                    xph[(size_t)orow * HD + c0 + ci * 16 + r] = (_Float16)acc[mi][ci][j];
            }
        }
    }
    // fused attention scores: wave w == head w owns cols [w*64, w*64+64)
#pragma unroll
    for (int mi = 0; mi < 2; ++mi) {
#pragma unroll
        for (int j = 0; j < 4; ++j) {
            float vs = 0.f, vd = 0.f;
#pragma unroll
            for (int ci = 0; ci < 4; ++ci) {
                vs += acc[mi][ci][j] * asr[ci];
                vd += acc[mi][ci][j] * ads[ci];
            }
#pragma unroll
            for (int msk = 1; msk < 16; msk <<= 1) {
                vs += __shfl_xor(vs, msk);
                vd += __shfl_xor(vd, msk);
            }
            int orow = m0 + mi * 16 + kq * 4 + j;
            if (r == 0 && orow < n) {
                s_src[orow * 4 + w] = vs;
                s_dst[orow * 4 + w] = vd;
            }
        }
    }
}

// ---------- single-block exclusive scan over (deg+1), int4-vectorized ----------
#define SCAN_T 1024
__global__ __launch_bounds__(SCAN_T) void scan_kernel(const int* __restrict__ deg,
                                                      int* __restrict__ rowptr, int n) {
    __shared__ int sdata[SCAN_T];
    int t = threadIdx.x;
    int per = (n + SCAN_T - 1) / SCAN_T;
    int begin = t * per;
    int endi = begin + per;
    if (endi > n) endi = n;
    if (begin > n) begin = n;
    bool vec = ((begin & 3) == 0) && (((endi - begin) & 3) == 0);
    int s = 0;
    if (vec) {
        for (int i = begin; i < endi; i += 4) {
            int4 v = *(const int4*)&deg[i];
            s += v.x + v.y + v.z + v.w + 4;
        }
    } else {
        for (int i = begin; i < endi; ++i) s += deg[i] + 1;
    }
    sdata[t] = s;
    __syncthreads();
    for (int off = 1; off < SCAN_T; off <<= 1) {
        int v = 0;
        if (t >= off) v = sdata[t - off];
        __syncthreads();
        sdata[t] += v;
        __syncthreads();
    }
    int run = (t == 0) ? 0 : sdata[t - 1];
    if (vec) {
        for (int i = begin; i < endi; i += 4) {
            int4 v = *(const int4*)&deg[i];
            int4 o;
            o.x = run; run += v.x + 1;
            o.y = run; run += v.y + 1;
            o.z = run; run += v.z + 1;
            o.w = run; run += v.w + 1;
            *(int4*)&rowptr[i] = o;
        }
    } else {
        for (int i = begin; i < endi; ++i) {
            rowptr[i] = run;
            run += deg[i] + 1;
        }
    }
    if (t == SCAN_T - 1) rowptr[n] = run;
}

// ---------- edge scoring + exp + CSR placement (atomic-free) ----------
__global__ __launch_bounds__(NTHR) void edge_kernel(const int* __restrict__ ei,
                                                    const float* __restrict__ ea,
                                                    const float* __restrict__ s_src,
                                                    const float* __restrict__ s_dst,
                                                    const float* __restrict__ weff,
                                                    const int* __restrict__ rowptr,
                                                    const int* __restrict__ perm,
                                                    const int* __restrict__ off_g,
                                                    int* __restrict__ src_csr,
                                                    float* __restrict__ p_csr,
                                                    int chunk, int use_off, int E, int n) {
    int is64 = detect64(ei);
    __shared__ float we[128];
    if (threadIdx.x < 128) we[threadIdx.x] = weff[threadIdx.x];
    __syncthreads();
    int e = blockIdx.x * blockDim.x + threadIdx.x;
    int EP = E + n;
    if (e >= EP) return;
    int s, d;
    load_edge(ei, e, E, n, is64, s, d);
    int pos;
    if (e < E) {
        int extra = use_off ? off_g[(size_t)(e / chunk) * n + d] : 0;
        pos = rowptr[d] + extra + perm[e];
    } else {
        pos = rowptr[d + 1] - 1;   // self-loop takes last slot of bucket
    }
    float4 vs = *(const float4*)&s_src[(size_t)s * 4];
    float4 vd = *(const float4*)&s_dst[(size_t)d * 4];
    float ed[4] = {0.f, 0.f, 0.f, 0.f};
    if (e < E) {
#pragma unroll
        for (int k = 0; k < EDGE_DIM; k += 4) {
            float4 v = *(const float4*)&ea[(size_t)e * EDGE_DIM + k];
#pragma unroll
            for (int h = 0; h < 4; ++h) {
                ed[h] += v.x * we[h * 32 + k + 0] + v.y * we[h * 32 + k + 1] +
                         v.z * we[h * 32 + k + 2] + v.w * we[h * 32 + k + 3];
            }
        }
    }
    float t0 = vs.x + vd.x + ed[0];
    float t1 = vs.y + vd.y + ed[1];
    float t2 = vs.z + vd.z + ed[2];
    float t3 = vs.w + vd.w + ed[3];
    t0 = t0 >= 0.f ? t0 : NEG_SLOPE * t0;
    t1 = t1 >= 0.f ? t1 : NEG_SLOPE * t1;
    t2 = t2 >= 0.f ? t2 : NEG_SLOPE * t2;
    t3 = t3 >= 0.f ? t3 : NEG_SLOPE * t3;
    float4 o;
    o.x = __expf(t0);
    o.y = __expf(t1);
    o.z = __expf(t2);
    o.w = __expf(t3);
    src_csr[pos] = s;
    *(float4*)&p_csr[(size_t)pos * 4] = o;
}

// ---------- aggregation: one wave per node, single pass, deferred normalization ----------
__global__ __launch_bounds__(NTHR) void agg_kernel(const int* __restrict__ rowptr,
                                                   const int* __restrict__ src_csr,
                                                   const float* __restrict__ p_csr,
                                                   const _Float16* __restrict__ xph,
                                                   const float* __restrict__ bias,
                                                   float* __restrict__ out, int n) {
    int wid = (blockIdx.x * blockDim.x + threadIdx.x) >> 6;
    int lane = threadIdx.x & 63;
    if (wid >= n) return;
    int start = rowptr[wid];
    int end = rowptr[wid + 1];
    int h = lane >> 4;

    float dh = 0.f, ax = 0.f, ay = 0.f, az = 0.f, aw = 0.f;
    int i = start;
    for (; i + 8 <= end; i += 8) {
        int s_[8];
        float p_[8];
        f16x4 xv[8];
#pragma unroll
        for (int j = 0; j < 8; ++j) s_[j] = src_csr[i + j];
#pragma unroll
        for (int j = 0; j < 8; ++j) p_[j] = p_csr[(size_t)(i + j) * 4 + h];
#pragma unroll
        for (int j = 0; j < 8; ++j)
            xv[j] = *(const f16x4*)&xph[(size_t)s_[j] * HD + lane * 4];
#pragma unroll
        for (int j = 0; j < 8; ++j) {
            dh += p_[j];
            ax += p_[j] * (float)xv[j][0];
            ay += p_[j] * (float)xv[j][1];
            az += p_[j] * (float)xv[j][2];
            aw += p_[j] * (float)xv[j][3];
        }
    }
    for (; i < end; ++i) {
        int s0 = src_csr[i];
        float p0 = p_csr[(size_t)i * 4 + h];
        f16x4 x0 = *(const f16x4*)&xph[(size_t)s0 * HD + lane * 4];
        dh += p0;
        ax += p0 * (float)x0[0];
        ay += p0 * (float)x0[1];
        az += p0 * (float)x0[2];
        aw += p0 * (float)x0[3];
    }
    float invh = 1.f / (dh + 1e-12f);
    float4 b = *(const float4*)&bias[lane * 4];
    float4 o4;
    o4.x = ax * invh + b.x;
    o4.y = ay * invh + b.y;
    o4.z = az * invh + b.z;
    o4.w = aw * invh + b.w;
    *(float4*)&out[(size_t)wid * HD + lane * 4] = o4;
}

extern "C" void kernel_launch(void* const* d_in, const int* in_sizes, int n_in,
                              void* d_out, int out_size, void* d_ws, size_t ws_size,
                              hipStream_t stream) {
    const float* x        = (const float*)d_in[0];
    const int*   ei       = (const int*)d_in[1];
    const float* ea       = (const float*)d_in[2];
    const float* lin_W    = (const float*)d_in[3];
    const float* att_src  = (const float*)d_in[4];
    const float* att_dst  = (const float*)d_in[5];
    const float* lin_eW   = (const float*)d_in[6];
    const float* att_edge = (const float*)d_in[7];
    const float* bias     = (const float*)d_in[8];
    float* out = (float*)d_out;

    int n  = in_sizes[0] / IN_DIM;     // 20000
    int E  = in_sizes[2] / EDGE_DIM;   // 320000
    int EP = E + n;
    int nw = (n + 1) >> 1;

    char* p = (char*)d_ws;
    auto alloc = [&](size_t bytes) {
        char* r = p;
        p += (bytes + 255) & ~(size_t)255;
        return r;
    };
    _Float16* xph   = (_Float16*)alloc((size_t)n * HD * 2);
    _Float16* Whr   = (_Float16*)alloc((size_t)HD * IN_DIM * 2);
    float* s_src    = (float*)alloc((size_t)n * 4 * 4);
    float* s_dst    = (float*)alloc((size_t)n * 4 * 4);
    float* p_csr    = (float*)alloc((size_t)EP * 4 * 4);
    float* weff     = (float*)alloc(128 * 4);
    int*   deg      = (int*)alloc((size_t)(n + 4) * 4);
    int*   rowptr   = (int*)alloc((size_t)(n + 1) * 4);
    int*   perm     = (int*)alloc((size_t)E * 4);
    int*   src_csr  = (int*)alloc((size_t)EP * 4);
    int*   cnt_g    = (int*)alloc((size_t)NB * nw * 4);
    int*   off_g    = (int*)alloc((size_t)NB * n * 4);

    int n4 = (n + 3) & ~3;
    int ZV = (n4 + 1023) / 1024;
    int chunk = (E + NB - 1) / NB;
    bool lds_ok = (n <= 2 * LDSW);

    k_pre<<<1 + WCVT_VBS + ZV, NTHR, 0, stream>>>(lin_eW, att_edge, lin_W, weff, Whr,
                                                  deg, n4);
    if (lds_ok) {
        k_hist_lds<<<NB, NTHR, 0, stream>>>(ei, cnt_g, perm, chunk, E, n);
    } else {
        k_hist_glb<<<(E + 1023) / 1024, NTHR, 0, stream>>>(ei, deg, perm, E);
    }
    k_proj<<<(n + 31) / 32, NTHR, 0, stream>>>(x, Whr, att_src, att_dst, xph,
                                               s_src, s_dst, n);
    if (lds_ok) {
        k_h2<<<(nw + NTHR - 1) / NTHR, NTHR, 0, stream>>>(cnt_g, off_g, deg, n);
    }
    scan_kernel<<<1, SCAN_T, 0, stream>>>(deg, rowptr, n);
    edge_kernel<<<(EP + NTHR - 1) / NTHR, NTHR, 0, stream>>>(
        ei, ea, s_src, s_dst, weff, rowptr, perm, off_g, src_csr, p_csr,
        chunk, lds_ok ? 1 : 0, E, n);
    agg_kernel<<<(n + 3) / 4, NTHR, 0, stream>>>(rowptr, src_csr, p_csr, xph, bias, out, n);
}

// Round 15
// 97.107 us; speedup vs baseline: 1.2424x; 1.2424x over previous
//
#include <hip/hip_runtime.h>
#include <math.h>

#define IN_DIM 256
#define HD 256
#define EDGE_DIM 32
#define NEG_SLOPE 0.2f
#define NTHR 256
#define WCVT_VBS 32

typedef _Float16 f16x8 __attribute__((ext_vector_type(8)));
typedef _Float16 f16x4 __attribute__((ext_vector_type(4)));
typedef float f32x4 __attribute__((ext_vector_type(4)));

__device__ __forceinline__ f16x8 cvt8(const float* p) {
    float4 lo = *(const float4*)p;
    float4 hi = *(const float4*)(p + 4);
    auto a = __builtin_amdgcn_cvt_pkrtz(lo.x, lo.y);
    auto b = __builtin_amdgcn_cvt_pkrtz(lo.z, lo.w);
    auto c = __builtin_amdgcn_cvt_pkrtz(hi.x, hi.y);
    auto d = __builtin_amdgcn_cvt_pkrtz(hi.z, hi.w);
    f16x8 r;
    r[0] = (_Float16)a[0]; r[1] = (_Float16)a[1];
    r[2] = (_Float16)b[0]; r[3] = (_Float16)b[1];
    r[4] = (_Float16)c[0]; r[5] = (_Float16)c[1];
    r[6] = (_Float16)d[0]; r[7] = (_Float16)d[1];
    return r;
}

// per-block int64-vs-int32 detect: high words of int64 node ids are all zero
__device__ __forceinline__ int detect64(const int* __restrict__ ei) {
    __shared__ int anynz;
    if (threadIdx.x == 0) anynz = 0;
    __syncthreads();
    if (ei[2 * threadIdx.x + 1] != 0) atomicOr(&anynz, 1);
    __syncthreads();
    return anynz == 0;
}

__device__ __forceinline__ void load_edge(const int* ei, int e, int E, int n, int is64,
                                          int& s, int& d) {
    if (e < E) {
        if (is64) { s = ei[2 * e]; d = ei[2 * E + 2 * e]; }
        else      { s = ei[e];     d = ei[E + e]; }
    } else {
        s = d = e - E;  // self loop
    }
}

// ---------- k_pre: weff (b0) | W->fp16 k-major repack (b1..32) | zero deg (b33..) ----------
// Whr layout: [k/8][col][8] f16 -> proj's B-fragment load is 256B contiguous per wave.
__global__ __launch_bounds__(NTHR) void k_pre(const float* __restrict__ lew,
                                              const float* __restrict__ ae,
                                              const float* __restrict__ W,
                                              float* __restrict__ weff,
                                              _Float16* __restrict__ Whr,
                                              int* __restrict__ deg, int n4) {
    int b = blockIdx.x;
    int t = threadIdx.x;
    if (b == 0) {
        if (t < 128) {
            int h = t >> 5, k = t & 31;
            float s = 0.f;
#pragma unroll 8
            for (int d = 0; d < 64; ++d) s += lew[(h * 64 + d) * 32 + k] * ae[h * 64 + d];
            weff[t] = s;
        }
    } else if (b <= WCVT_VBS) {
        int idx = (b - 1) * 2048 + t * 8;   // element index into row-major W (col*256+k)
        int col = idx >> 8;
        int k = idx & 255;                  // 8 consecutive k
        f16x8 v = cvt8(&W[idx]);
        *(f16x8*)&Whr[(size_t)(k >> 3) * 2048 + col * 8] = v;
    } else {
        int i = (b - 1 - WCVT_VBS) * 1024 + t * 4;
        if (i < n4) *(int4*)&deg[i] = make_int4(0, 0, 0, 0);
    }
}

// ---------- k_hist: global-atomic degree histogram + perm (4 edges/thread) ----------
__global__ __launch_bounds__(NTHR) void k_hist(const int* __restrict__ ei,
                                               int* __restrict__ deg,
                                               int* __restrict__ perm, int E) {
    int is64 = detect64(ei);
    int e0 = (blockIdx.x * NTHR + threadIdx.x) * 4;
    if (e0 >= E) return;
    if (e0 + 4 <= E) {
        int4 pm;
        if (!is64) {
            int4 d4 = *(const int4*)&ei[E + e0];
            pm.x = atomicAdd(&deg[d4.x], 1);
            pm.y = atomicAdd(&deg[d4.y], 1);
            pm.z = atomicAdd(&deg[d4.z], 1);
            pm.w = atomicAdd(&deg[d4.w], 1);
        } else {
            int4 a = *(const int4*)&ei[2 * E + 2 * e0];
            int4 b4 = *(const int4*)&ei[2 * E + 2 * e0 + 4];
            pm.x = atomicAdd(&deg[a.x], 1);
            pm.y = atomicAdd(&deg[a.z], 1);
            pm.z = atomicAdd(&deg[b4.x], 1);
            pm.w = atomicAdd(&deg[b4.z], 1);
        }
        *(int4*)&perm[e0] = pm;
    } else {
        for (int e = e0; e < E && e < e0 + 4; ++e) {
            int d = is64 ? ei[2 * E + 2 * e] : ei[E + e];
            perm[e] = atomicAdd(&deg[d], 1);
        }
    }
}

// ---------- k_proj: 32 rows/block; x staged in LDS (f16, k-major planes); Whr coalesced ----
#define XPLN 33
__global__ __launch_bounds__(NTHR) void k_proj(const float* __restrict__ x,
                                               const _Float16* __restrict__ Whr,
                                               const float* __restrict__ asrc_g,
                                               const float* __restrict__ adst_g,
                                               _Float16* __restrict__ xph,
                                               float* __restrict__ s_src,
                                               float* __restrict__ s_dst, int n) {
    __shared__ _Float16 xs[32 * XPLN * 8];   // 16.9 KB
    int t = threadIdx.x;
    int lane = t & 63;
    int w = t >> 6;              // wave id == head id (col group)
    int m0 = blockIdx.x * 32;
    int c0 = w * 64;
    int r = lane & 15;
    int kq = lane >> 4;          // 0..3

    // ---- stage 32 x-rows -> LDS f16 (coalesced 128B per thread) ----
    {
        int rr = t >> 3;               // 0..31
        int kc = (t & 7) * 32;         // 0..224
        int grow = m0 + rr;
        if (grow < n) {
            const float* xp = &x[(size_t)grow * IN_DIM + kc];
#pragma unroll
            for (int c4 = 0; c4 < 4; ++c4) {
                f16x8 v = cvt8(xp + c4 * 8);
                *(f16x8*)&xs[(size_t)((kc >> 3) + c4) * (XPLN * 8) + rr * 8] = v;
            }
        } else {
            f16x8 z = {0, 0, 0, 0, 0, 0, 0, 0};
#pragma unroll
            for (int c4 = 0; c4 < 4; ++c4)
                *(f16x8*)&xs[(size_t)((kc >> 3) + c4) * (XPLN * 8) + rr * 8] = z;
        }
    }

    float asr[4], ads[4];
#pragma unroll
    for (int ci = 0; ci < 4; ++ci) {
        asr[ci] = asrc_g[c0 + ci * 16 + r];
        ads[ci] = adst_g[c0 + ci * 16 + r];
    }

    f32x4 acc[2][4];
#pragma unroll
    for (int mi = 0; mi < 2; ++mi)
#pragma unroll
        for (int j = 0; j < 4; ++j) acc[mi][j] = (f32x4){0.f, 0.f, 0.f, 0.f};

    __syncthreads();

#pragma unroll
    for (int k0 = 0; k0 < IN_DIM; k0 += 32) {
        int p = (k0 >> 3) + kq;
        f16x8 a0 = *(const f16x8*)&xs[(size_t)p * (XPLN * 8) + (0 * 16 + r) * 8];
        f16x8 a1 = *(const f16x8*)&xs[(size_t)p * (XPLN * 8) + (1 * 16 + r) * 8];
        f16x8 bfr[4];
#pragma unroll
        for (int ci = 0; ci < 4; ++ci)
            bfr[ci] = *(const f16x8*)&Whr[(size_t)p * 2048 + (c0 + ci * 16 + r) * 8];
#pragma unroll
        for (int ci = 0; ci < 4; ++ci) {
            acc[0][ci] = __builtin_amdgcn_mfma_f32_16x16x32_f16(a0, bfr[ci], acc[0][ci],
                                                                0, 0, 0);
            acc[1][ci] = __builtin_amdgcn_mfma_f32_16x16x32_f16(a1, bfr[ci], acc[1][ci],
                                                                0, 0, 0);
        }
    }
    // C/D layout: col = lane&15, row = (lane>>4)*4 + j
#pragma unroll
    for (int mi = 0; mi < 2; ++mi) {
#pragma unroll
        for (int j = 0; j < 4; ++j) {
            int orow = m0 + mi * 16 + kq * 4 + j;
            if (orow < n) {
#pragma unroll
                for (int ci = 0; ci < 4; ++ci)
                    xph[(size_t)orow * HD + c0 + ci * 16 + r] = (_Float16)acc[mi][ci][j];
            }
        }
    }
    // fused attention scores: wave w == head w owns cols [w*64, w*64+64)
#pragma unroll
    for (int mi = 0; mi < 2; ++mi) {
#pragma unroll
        for (int j = 0; j < 4; ++j) {
            float vs = 0.f, vd = 0.f;
#pragma unroll
            for (int ci = 0; ci < 4; ++ci) {
                vs += acc[mi][ci][j] * asr[ci];
                vd += acc[mi][ci][j] * ads[ci];
            }
#pragma unroll
            for (int msk = 1; msk < 16; msk <<= 1) {
                vs += __shfl_xor(vs, msk);
                vd += __shfl_xor(vd, msk);
            }
            int orow = m0 + mi * 16 + kq * 4 + j;
            if (r == 0 && orow < n) {
                s_src[orow * 4 + w] = vs;
                s_dst[orow * 4 + w] = vd;
            }
        }
    }
}

// ---------- single-block exclusive scan over (deg+1), int4-vectorized ----------
#define SCAN_T 1024
__global__ __launch_bounds__(SCAN_T) void scan_kernel(const int* __restrict__ deg,
                                                      int* __restrict__ rowptr, int n) {
    __shared__ int sdata[SCAN_T];
    int t = threadIdx.x;
    int per = (n + SCAN_T - 1) / SCAN_T;
    int begin = t * per;
    int endi = begin + per;
    if (endi > n) endi = n;
    if (begin > n) begin = n;
    bool vec = ((begin & 3) == 0) && (((endi - begin) & 3) == 0);
    int s = 0;
    if (vec) {
        for (int i = begin; i < endi; i += 4) {
            int4 v = *(const int4*)&deg[i];
            s += v.x + v.y + v.z + v.w + 4;
        }
    } else {
        for (int i = begin; i < endi; ++i) s += deg[i] + 1;
    }
    sdata[t] = s;
    __syncthreads();
    for (int off = 1; off < SCAN_T; off <<= 1) {
        int v = 0;
        if (t >= off) v = sdata[t - off];
        __syncthreads();
        sdata[t] += v;
        __syncthreads();
    }
    int run = (t == 0) ? 0 : sdata[t - 1];
    if (vec) {
        for (int i = begin; i < endi; i += 4) {
            int4 v = *(const int4*)&deg[i];
            int4 o;
            o.x = run; run += v.x + 1;
            o.y = run; run += v.y + 1;
            o.z = run; run += v.z + 1;
            o.w = run; run += v.w + 1;
            *(int4*)&rowptr[i] = o;
        }
    } else {
        for (int i = begin; i < endi; ++i) {
            rowptr[i] = run;
            run += deg[i] + 1;
        }
    }
    if (t == SCAN_T - 1) rowptr[n] = run;
}

// ---------- edge scoring + exp + CSR placement; packed 32B record (src, p[4]) ----------
// rec[pos] occupies 32B: [0:4)=src, [16:32)=p (float4). One 64B line touched per edge.
__global__ __launch_bounds__(NTHR) void edge_kernel(const int* __restrict__ ei,
                                                    const float* __restrict__ ea,
                                                    const float* __restrict__ s_src,
                                                    const float* __restrict__ s_dst,
                                                    const float* __restrict__ weff,
                                                    const int* __restrict__ rowptr,
                                                    const int* __restrict__ perm,
                                                    char* __restrict__ rec,
                                                    int E, int n) {
    int is64 = detect64(ei);
    __shared__ float we[128];
    if (threadIdx.x < 128) we[threadIdx.x] = weff[threadIdx.x];
    __syncthreads();
    int e = blockIdx.x * blockDim.x + threadIdx.x;
    int EP = E + n;
    if (e >= EP) return;
    int s, d;
    load_edge(ei, e, E, n, is64, s, d);
    int pos;
    if (e < E) pos = rowptr[d] + perm[e];
    else       pos = rowptr[d + 1] - 1;   // self-loop takes last slot of bucket
    float4 vs = *(const float4*)&s_src[(size_t)s * 4];
    float4 vd = *(const float4*)&s_dst[(size_t)d * 4];
    float ed[4] = {0.f, 0.f, 0.f, 0.f};
    if (e < E) {
#pragma unroll
        for (int k = 0; k < EDGE_DIM; k += 4) {
            float4 v = *(const float4*)&ea[(size_t)e * EDGE_DIM + k];
#pragma unroll
            for (int h = 0; h < 4; ++h) {
                ed[h] += v.x * we[h * 32 + k + 0] + v.y * we[h * 32 + k + 1] +
                         v.z * we[h * 32 + k + 2] + v.w * we[h * 32 + k + 3];
            }
        }
    }
    float t0 = vs.x + vd.x + ed[0];
    float t1 = vs.y + vd.y + ed[1];
    float t2 = vs.z + vd.z + ed[2];
    float t3 = vs.w + vd.w + ed[3];
    t0 = t0 >= 0.f ? t0 : NEG_SLOPE * t0;
    t1 = t1 >= 0.f ? t1 : NEG_SLOPE * t1;
    t2 = t2 >= 0.f ? t2 : NEG_SLOPE * t2;
    t3 = t3 >= 0.f ? t3 : NEG_SLOPE * t3;
    float4 o;
    o.x = __expf(t0);
    o.y = __expf(t1);
    o.z = __expf(t2);
    o.w = __expf(t3);
    char* rp = rec + (size_t)pos * 32;
    *(int4*)rp = make_int4(s, 0, 0, 0);
    *(float4*)(rp + 16) = o;
}

// ---------- aggregation: one wave per node, single pass, packed-record reads ----------
__global__ __launch_bounds__(NTHR) void agg_kernel(const int* __restrict__ rowptr,
                                                   const char* __restrict__ rec,
                                                   const _Float16* __restrict__ xph,
                                                   const float* __restrict__ bias,
                                                   float* __restrict__ out, int n) {
    int wid = (blockIdx.x * blockDim.x + threadIdx.x) >> 6;
    int lane = threadIdx.x & 63;
    if (wid >= n) return;
    int start = rowptr[wid];
    int end = rowptr[wid + 1];
    int h = lane >> 4;

    float dh = 0.f, ax = 0.f, ay = 0.f, az = 0.f, aw = 0.f;
    int i = start;
    for (; i + 8 <= end; i += 8) {
        int s_[8];
        float p_[8];
        f16x4 xv[8];
#pragma unroll
        for (int j = 0; j < 8; ++j) {
            const char* rp = rec + (size_t)(i + j) * 32;
            s_[j] = *(const int*)rp;
            p_[j] = *(const float*)(rp + 16 + h * 4);
        }
#pragma unroll
        for (int j = 0; j < 8; ++j)
            xv[j] = *(const f16x4*)&xph[(size_t)s_[j] * HD + lane * 4];
#pragma unroll
        for (int j = 0; j < 8; ++j) {
            dh += p_[j];
            ax += p_[j] * (float)xv[j][0];
            ay += p_[j] * (float)xv[j][1];
            az += p_[j] * (float)xv[j][2];
            aw += p_[j] * (float)xv[j][3];
        }
    }
    for (; i < end; ++i) {
        const char* rp = rec + (size_t)i * 32;
        int s0 = *(const int*)rp;
        float p0 = *(const float*)(rp + 16 + h * 4);
        f16x4 x0 = *(const f16x4*)&xph[(size_t)s0 * HD + lane * 4];
        dh += p0;
        ax += p0 * (float)x0[0];
        ay += p0 * (float)x0[1];
        az += p0 * (float)x0[2];
        aw += p0 * (float)x0[3];
    }
    float invh = 1.f / (dh + 1e-12f);
    float4 b = *(const float4*)&bias[lane * 4];
    float4 o4;
    o4.x = ax * invh + b.x;
    o4.y = ay * invh + b.y;
    o4.z = az * invh + b.z;
    o4.w = aw * invh + b.w;
    *(float4*)&out[(size_t)wid * HD + lane * 4] = o4;
}

extern "C" void kernel_launch(void* const* d_in, const int* in_sizes, int n_in,
                              void* d_out, int out_size, void* d_ws, size_t ws_size,
                              hipStream_t stream) {
    const float* x        = (const float*)d_in[0];
    const int*   ei       = (const int*)d_in[1];
    const float* ea       = (const float*)d_in[2];
    const float* lin_W    = (const float*)d_in[3];
    const float* att_src  = (const float*)d_in[4];
    const float* att_dst  = (const float*)d_in[5];
    const float* lin_eW   = (const float*)d_in[6];
    const float* att_edge = (const float*)d_in[7];
    const float* bias     = (const float*)d_in[8];
    float* out = (float*)d_out;

    int n  = in_sizes[0] / IN_DIM;     // 20000
    int E  = in_sizes[2] / EDGE_DIM;   // 320000
    int EP = E + n;

    char* p = (char*)d_ws;
    auto alloc = [&](size_t bytes) {
        char* r = p;
        p += (bytes + 255) & ~(size_t)255;
        return r;
    };
    _Float16* xph   = (_Float16*)alloc((size_t)n * HD * 2);
    _Float16* Whr   = (_Float16*)alloc((size_t)HD * IN_DIM * 2);
    float* s_src    = (float*)alloc((size_t)n * 4 * 4);
    float* s_dst    = (float*)alloc((size_t)n * 4 * 4);
    char*  rec      = (char*)alloc((size_t)EP * 32);
    float* weff     = (float*)alloc(128 * 4);
    int*   deg      = (int*)alloc((size_t)(n + 4) * 4);
    int*   rowptr   = (int*)alloc((size_t)(n + 1) * 4);
    int*   perm     = (int*)alloc((size_t)E * 4);

    int n4 = (n + 3) & ~3;
    int ZV = (n4 + 1023) / 1024;

    k_pre<<<1 + WCVT_VBS + ZV, NTHR, 0, stream>>>(lin_eW, att_edge, lin_W, weff, Whr,
                                                  deg, n4);
    k_hist<<<(E + 1023) / 1024, NTHR, 0, stream>>>(ei, deg, perm, E);
    k_proj<<<(n + 31) / 32, NTHR, 0, stream>>>(x, Whr, att_src, att_dst, xph,
                                               s_src, s_dst, n);
    scan_kernel<<<1, SCAN_T, 0, stream>>>(deg, rowptr, n);
    edge_kernel<<<(EP + NTHR - 1) / NTHR, NTHR, 0, stream>>>(ei, ea, s_src, s_dst, weff,
                                                             rowptr, perm, rec, E, n);
    agg_kernel<<<(n + 3) / 4, NTHR, 0, stream>>>(rowptr, rec, xph, bias, out, n);
}

// Round 16
// 93.732 us; speedup vs baseline: 1.2871x; 1.0360x over previous
//
#include <hip/hip_runtime.h>
#include <math.h>

#define IN_DIM 256
#define HD 256
#define EDGE_DIM 32
#define NEG_SLOPE 0.2f
#define NTHR 256
#define WCVT_VBS 32

typedef _Float16 f16x8 __attribute__((ext_vector_type(8)));
typedef _Float16 f16x4 __attribute__((ext_vector_type(4)));
typedef float f32x4 __attribute__((ext_vector_type(4)));

__device__ __forceinline__ f16x8 cvt8(const float* p) {
    float4 lo = *(const float4*)p;
    float4 hi = *(const float4*)(p + 4);
    auto a = __builtin_amdgcn_cvt_pkrtz(lo.x, lo.y);
    auto b = __builtin_amdgcn_cvt_pkrtz(lo.z, lo.w);
    auto c = __builtin_amdgcn_cvt_pkrtz(hi.x, hi.y);
    auto d = __builtin_amdgcn_cvt_pkrtz(hi.z, hi.w);
    f16x8 r;
    r[0] = (_Float16)a[0]; r[1] = (_Float16)a[1];
    r[2] = (_Float16)b[0]; r[3] = (_Float16)b[1];
    r[4] = (_Float16)c[0]; r[5] = (_Float16)c[1];
    r[6] = (_Float16)d[0]; r[7] = (_Float16)d[1];
    return r;
}

// per-block int64-vs-int32 detect: high words of int64 node ids are all zero
__device__ __forceinline__ int detect64(const int* __restrict__ ei) {
    __shared__ int anynz;
    if (threadIdx.x == 0) anynz = 0;
    __syncthreads();
    if (ei[2 * threadIdx.x + 1] != 0) atomicOr(&anynz, 1);
    __syncthreads();
    return anynz == 0;
}

__device__ __forceinline__ void load_edge(const int* ei, int e, int E, int n, int is64,
                                          int& s, int& d) {
    if (e < E) {
        if (is64) { s = ei[2 * e]; d = ei[2 * E + 2 * e]; }
        else      { s = ei[e];     d = ei[E + e]; }
    } else {
        s = d = e - E;  // self loop
    }
}

// ---------- k_pre: weff (b0) | W->fp16 k-major repack (b1..32) | zero deg (b33..) ----------
// Whr layout: [k/8][col][8] f16 -> proj's B-fragment load is 256B contiguous per wave.
__global__ __launch_bounds__(NTHR) void k_pre(const float* __restrict__ lew,
                                              const float* __restrict__ ae,
                                              const float* __restrict__ W,
                                              float* __restrict__ weff,
                                              _Float16* __restrict__ Whr,
                                              int* __restrict__ deg, int n4) {
    int b = blockIdx.x;
    int t = threadIdx.x;
    if (b == 0) {
        if (t < 128) {
            int h = t >> 5, k = t & 31;
            float s = 0.f;
#pragma unroll 8
            for (int d = 0; d < 64; ++d) s += lew[(h * 64 + d) * 32 + k] * ae[h * 64 + d];
            weff[t] = s;
        }
    } else if (b <= WCVT_VBS) {
        int idx = (b - 1) * 2048 + t * 8;   // element index into row-major W (col*256+k)
        int col = idx >> 8;
        int k = idx & 255;                  // 8 consecutive k
        f16x8 v = cvt8(&W[idx]);
        *(f16x8*)&Whr[(size_t)(k >> 3) * 2048 + col * 8] = v;
    } else {
        int i = (b - 1 - WCVT_VBS) * 1024 + t * 4;
        if (i < n4) *(int4*)&deg[i] = make_int4(0, 0, 0, 0);
    }
}

// ---------- k_hist: global-atomic degree histogram + perm (4 edges/thread) ----------
__global__ __launch_bounds__(NTHR) void k_hist(const int* __restrict__ ei,
                                               int* __restrict__ deg,
                                               int* __restrict__ perm, int E) {
    int is64 = detect64(ei);
    int e0 = (blockIdx.x * NTHR + threadIdx.x) * 4;
    if (e0 >= E) return;
    if (e0 + 4 <= E) {
        int4 pm;
        if (!is64) {
            int4 d4 = *(const int4*)&ei[E + e0];
            pm.x = atomicAdd(&deg[d4.x], 1);
            pm.y = atomicAdd(&deg[d4.y], 1);
            pm.z = atomicAdd(&deg[d4.z], 1);
            pm.w = atomicAdd(&deg[d4.w], 1);
        } else {
            int4 a = *(const int4*)&ei[2 * E + 2 * e0];
            int4 b4 = *(const int4*)&ei[2 * E + 2 * e0 + 4];
            pm.x = atomicAdd(&deg[a.x], 1);
            pm.y = atomicAdd(&deg[a.z], 1);
            pm.z = atomicAdd(&deg[b4.x], 1);
            pm.w = atomicAdd(&deg[b4.z], 1);
        }
        *(int4*)&perm[e0] = pm;
    } else {
        for (int e = e0; e < E && e < e0 + 4; ++e) {
            int d = is64 ? ei[2 * E + 2 * e] : ei[E + e];
            perm[e] = atomicAdd(&deg[d], 1);
        }
    }
}

// ---------- k_proj: 32 rows/block; x staged in LDS (f16, k-major planes); Whr coalesced ----
#define XPLN 33
__global__ __launch_bounds__(NTHR) void k_proj(const float* __restrict__ x,
                                               const _Float16* __restrict__ Whr,
                                               const float* __restrict__ asrc_g,
                                               const float* __restrict__ adst_g,
                                               _Float16* __restrict__ xph,
                                               float* __restrict__ s_src,
                                               float* __restrict__ s_dst, int n) {
    __shared__ _Float16 xs[32 * XPLN * 8];   // 16.9 KB
    int t = threadIdx.x;
    int lane = t & 63;
    int w = t >> 6;              // wave id == head id (col group)
    int m0 = blockIdx.x * 32;
    int c0 = w * 64;
    int r = lane & 15;
    int kq = lane >> 4;          // 0..3

    // ---- stage 32 x-rows -> LDS f16 (coalesced 128B per thread) ----
    {
        int rr = t >> 3;               // 0..31
        int kc = (t & 7) * 32;         // 0..224
        int grow = m0 + rr;
        if (grow < n) {
            const float* xp = &x[(size_t)grow * IN_DIM + kc];
#pragma unroll
            for (int c4 = 0; c4 < 4; ++c4) {
                f16x8 v = cvt8(xp + c4 * 8);
                *(f16x8*)&xs[(size_t)((kc >> 3) + c4) * (XPLN * 8) + rr * 8] = v;
            }
        } else {
            f16x8 z = {0, 0, 0, 0, 0, 0, 0, 0};
#pragma unroll
            for (int c4 = 0; c4 < 4; ++c4)
                *(f16x8*)&xs[(size_t)((kc >> 3) + c4) * (XPLN * 8) + rr * 8] = z;
        }
    }

    float asr[4], ads[4];
#pragma unroll
    for (int ci = 0; ci < 4; ++ci) {
        asr[ci] = asrc_g[c0 + ci * 16 + r];
        ads[ci] = adst_g[c0 + ci * 16 + r];
    }

    f32x4 acc[2][4];
#pragma unroll
    for (int mi = 0; mi < 2; ++mi)
#pragma unroll
        for (int j = 0; j < 4; ++j) acc[mi][j] = (f32x4){0.f, 0.f, 0.f, 0.f};

    __syncthreads();

#pragma unroll
    for (int k0 = 0; k0 < IN_DIM; k0 += 32) {
        int p = (k0 >> 3) + kq;
        f16x8 a0 = *(const f16x8*)&xs[(size_t)p * (XPLN * 8) + (0 * 16 + r) * 8];
        f16x8 a1 = *(const f16x8*)&xs[(size_t)p * (XPLN * 8) + (1 * 16 + r) * 8];
        f16x8 bfr[4];
#pragma unroll
        for (int ci = 0; ci < 4; ++ci)
            bfr[ci] = *(const f16x8*)&Whr[(size_t)p * 2048 + (c0 + ci * 16 + r) * 8];
#pragma unroll
        for (int ci = 0; ci < 4; ++ci) {
            acc[0][ci] = __builtin_amdgcn_mfma_f32_16x16x32_f16(a0, bfr[ci], acc[0][ci],
                                                                0, 0, 0);
            acc[1][ci] = __builtin_amdgcn_mfma_f32_16x16x32_f16(a1, bfr[ci], acc[1][ci],
                                                                0, 0, 0);
        }
    }
    // C/D layout: col = lane&15, row = (lane>>4)*4 + j
#pragma unroll
    for (int mi = 0; mi < 2; ++mi) {
#pragma unroll
        for (int j = 0; j < 4; ++j) {
            int orow = m0 + mi * 16 + kq * 4 + j;
            if (orow < n) {
#pragma unroll
                for (int ci = 0; ci < 4; ++ci)
                    xph[(size_t)orow * HD + c0 + ci * 16 + r] = (_Float16)acc[mi][ci][j];
            }
        }
    }
    // fused attention scores: wave w == head w owns cols [w*64, w*64+64)
#pragma unroll
    for (int mi = 0; mi < 2; ++mi) {
#pragma unroll
        for (int j = 0; j < 4; ++j) {
            float vs = 0.f, vd = 0.f;
#pragma unroll
            for (int ci = 0; ci < 4; ++ci) {
                vs += acc[mi][ci][j] * asr[ci];
                vd += acc[mi][ci][j] * ads[ci];
            }
#pragma unroll
            for (int msk = 1; msk < 16; msk <<= 1) {
                vs += __shfl_xor(vs, msk);
                vd += __shfl_xor(vd, msk);
            }
            int orow = m0 + mi * 16 + kq * 4 + j;
            if (r == 0 && orow < n) {
                s_src[orow * 4 + w] = vs;
                s_dst[orow * 4 + w] = vd;
            }
        }
    }
}

// ---------- single-block exclusive scan over (deg+1), int4-vectorized ----------
#define SCAN_T 1024
__global__ __launch_bounds__(SCAN_T) void scan_kernel(const int* __restrict__ deg,
                                                      int* __restrict__ rowptr, int n) {
    __shared__ int sdata[SCAN_T];
    int t = threadIdx.x;
    int per = (n + SCAN_T - 1) / SCAN_T;
    int begin = t * per;
    int endi = begin + per;
    if (endi > n) endi = n;
    if (begin > n) begin = n;
    bool vec = ((begin & 3) == 0) && (((endi - begin) & 3) == 0);
    int s = 0;
    if (vec) {
        for (int i = begin; i < endi; i += 4) {
            int4 v = *(const int4*)&deg[i];
            s += v.x + v.y + v.z + v.w + 4;
        }
    } else {
        for (int i = begin; i < endi; ++i) s += deg[i] + 1;
    }
    sdata[t] = s;
    __syncthreads();
    for (int off = 1; off < SCAN_T; off <<= 1) {
        int v = 0;
        if (t >= off) v = sdata[t - off];
        __syncthreads();
        sdata[t] += v;
        __syncthreads();
    }
    int run = (t == 0) ? 0 : sdata[t - 1];
    if (vec) {
        for (int i = begin; i < endi; i += 4) {
            int4 v = *(const int4*)&deg[i];
            int4 o;
            o.x = run; run += v.x + 1;
            o.y = run; run += v.y + 1;
            o.z = run; run += v.z + 1;
            o.w = run; run += v.w + 1;
            *(int4*)&rowptr[i] = o;
        }
    } else {
        for (int i = begin; i < endi; ++i) {
            rowptr[i] = run;
            run += deg[i] + 1;
        }
    }
    if (t == SCAN_T - 1) rowptr[n] = run;
}

// ---------- edge scoring + exp + CSR placement; packed 32B record (src, p[4]) ----------
__global__ __launch_bounds__(NTHR) void edge_kernel(const int* __restrict__ ei,
                                                    const float* __restrict__ ea,
                                                    const float* __restrict__ s_src,
                                                    const float* __restrict__ s_dst,
                                                    const float* __restrict__ weff,
                                                    const int* __restrict__ rowptr,
                                                    const int* __restrict__ perm,
                                                    char* __restrict__ rec,
                                                    int E, int n) {
    int is64 = detect64(ei);
    __shared__ float we[128];
    if (threadIdx.x < 128) we[threadIdx.x] = weff[threadIdx.x];
    __syncthreads();
    int e = blockIdx.x * blockDim.x + threadIdx.x;
    int EP = E + n;
    if (e >= EP) return;
    int s, d;
    load_edge(ei, e, E, n, is64, s, d);
    int pos;
    if (e < E) pos = rowptr[d] + perm[e];
    else       pos = rowptr[d + 1] - 1;   // self-loop takes last slot of bucket
    float4 vs = *(const float4*)&s_src[(size_t)s * 4];
    float4 vd = *(const float4*)&s_dst[(size_t)d * 4];
    float ed[4] = {0.f, 0.f, 0.f, 0.f};
    if (e < E) {
#pragma unroll
        for (int k = 0; k < EDGE_DIM; k += 4) {
            float4 v = *(const float4*)&ea[(size_t)e * EDGE_DIM + k];
#pragma unroll
            for (int h = 0; h < 4; ++h) {
                ed[h] += v.x * we[h * 32 + k + 0] + v.y * we[h * 32 + k + 1] +
                         v.z * we[h * 32 + k + 2] + v.w * we[h * 32 + k + 3];
            }
        }
    }
    float t0 = vs.x + vd.x + ed[0];
    float t1 = vs.y + vd.y + ed[1];
    float t2 = vs.z + vd.z + ed[2];
    float t3 = vs.w + vd.w + ed[3];
    t0 = t0 >= 0.f ? t0 : NEG_SLOPE * t0;
    t1 = t1 >= 0.f ? t1 : NEG_SLOPE * t1;
    t2 = t2 >= 0.f ? t2 : NEG_SLOPE * t2;
    t3 = t3 >= 0.f ? t3 : NEG_SLOPE * t3;
    float4 o;
    o.x = __expf(t0);
    o.y = __expf(t1);
    o.z = __expf(t2);
    o.w = __expf(t3);
    char* rp = rec + (size_t)pos * 32;
    *(int4*)rp = make_int4(s, 0, 0, 0);
    *(float4*)(rp + 16) = o;
}

// ---------- aggregation v2: one wave per node, HALF-WAVE per edge, f16x8 loads ----------
// lanes 0-31 handle edges i, i+2, ...; lanes 32-63 handle i+1, i+3, ...
// lane covers dims [8l, 8l+8), head = l>>3. Final shfl_xor(32) combines the halves.
__global__ __launch_bounds__(NTHR) void agg_kernel(const int* __restrict__ rowptr,
                                                   const char* __restrict__ rec,
                                                   const _Float16* __restrict__ xph,
                                                   const float* __restrict__ bias,
                                                   float* __restrict__ out, int n) {
    int wid = (blockIdx.x * blockDim.x + threadIdx.x) >> 6;
    int lane = threadIdx.x & 63;
    if (wid >= n) return;
    int sub = lane >> 5;     // which edge of the pair
    int l = lane & 31;       // dim group: dims [8l, 8l+8)
    int h = l >> 3;          // head
    int start = rowptr[wid];
    int end = rowptr[wid + 1];

    float dh = 0.f;
    float acc[8];
#pragma unroll
    for (int k = 0; k < 8; ++k) acc[k] = 0.f;

    int i = start;
    for (; i + 4 <= end; i += 4) {
        const char* rp0 = rec + (size_t)(i + sub) * 32;
        const char* rp1 = rec + (size_t)(i + 2 + sub) * 32;
        int s0 = *(const int*)rp0;
        int s1 = *(const int*)rp1;
        float p0 = *(const float*)(rp0 + 16 + h * 4);
        float p1 = *(const float*)(rp1 + 16 + h * 4);
        f16x8 x0 = *(const f16x8*)&xph[(size_t)s0 * HD + l * 8];
        f16x8 x1 = *(const f16x8*)&xph[(size_t)s1 * HD + l * 8];
        dh += p0 + p1;
#pragma unroll
        for (int k = 0; k < 8; ++k)
            acc[k] += p0 * (float)x0[k] + p1 * (float)x1[k];
    }
    for (; i + 2 <= end; i += 2) {
        const char* rp0 = rec + (size_t)(i + sub) * 32;
        int s0 = *(const int*)rp0;
        float p0 = *(const float*)(rp0 + 16 + h * 4);
        f16x8 x0 = *(const f16x8*)&xph[(size_t)s0 * HD + l * 8];
        dh += p0;
#pragma unroll
        for (int k = 0; k < 8; ++k) acc[k] += p0 * (float)x0[k];
    }
    if (i < end && sub == 0) {
        const char* rp0 = rec + (size_t)i * 32;
        int s0 = *(const int*)rp0;
        float p0 = *(const float*)(rp0 + 16 + h * 4);
        f16x8 x0 = *(const f16x8*)&xph[(size_t)s0 * HD + l * 8];
        dh += p0;
#pragma unroll
        for (int k = 0; k < 8; ++k) acc[k] += p0 * (float)x0[k];
    }
    // combine the two halves
    dh += __shfl_xor(dh, 32);
#pragma unroll
    for (int k = 0; k < 8; ++k) acc[k] += __shfl_xor(acc[k], 32);
    float invh = 1.f / (dh + 1e-12f);
    // lane L (sub=0) writes dims [8l, 8l+4); lane L+32 writes [8l+4, 8l+8)
    float a0 = sub ? acc[4] : acc[0];
    float a1 = sub ? acc[5] : acc[1];
    float a2 = sub ? acc[6] : acc[2];
    float a3 = sub ? acc[7] : acc[3];
    int doff = l * 8 + sub * 4;
    float4 b = *(const float4*)&bias[doff];
    float4 o4;
    o4.x = a0 * invh + b.x;
    o4.y = a1 * invh + b.y;
    o4.z = a2 * invh + b.z;
    o4.w = a3 * invh + b.w;
    *(float4*)&out[(size_t)wid * HD + doff] = o4;
}

extern "C" void kernel_launch(void* const* d_in, const int* in_sizes, int n_in,
                              void* d_out, int out_size, void* d_ws, size_t ws_size,
                              hipStream_t stream) {
    const float* x        = (const float*)d_in[0];
    const int*   ei       = (const int*)d_in[1];
    const float* ea       = (const float*)d_in[2];
    const float* lin_W    = (const float*)d_in[3];
    const float* att_src  = (const float*)d_in[4];
    const float* att_dst  = (const float*)d_in[5];
    const float* lin_eW   = (const float*)d_in[6];
    const float* att_edge = (const float*)d_in[7];
    const float* bias     = (const float*)d_in[8];
    float* out = (float*)d_out;

    int n  = in_sizes[0] / IN_DIM;     // 20000
    int E  = in_sizes[2] / EDGE_DIM;   // 320000
    int EP = E + n;

    char* p = (char*)d_ws;
    auto alloc = [&](size_t bytes) {
        char* r = p;
        p += (bytes + 255) & ~(size_t)255;
        return r;
    };
    _Float16* xph   = (_Float16*)alloc((size_t)n * HD * 2);
    _Float16* Whr   = (_Float16*)alloc((size_t)HD * IN_DIM * 2);
    float* s_src    = (float*)alloc((size_t)n * 4 * 4);
    float* s_dst    = (float*)alloc((size_t)n * 4 * 4);
    char*  rec      = (char*)alloc((size_t)EP * 32);
    float* weff     = (float*)alloc(128 * 4);
    int*   deg      = (int*)alloc((size_t)(n + 4) * 4);
    int*   rowptr   = (int*)alloc((size_t)(n + 1) * 4);
    int*   perm     = (int*)alloc((size_t)E * 4);

    int n4 = (n + 3) & ~3;
    int ZV = (n4 + 1023) / 1024;

    k_pre<<<1 + WCVT_VBS + ZV, NTHR, 0, stream>>>(lin_eW, att_edge, lin_W, weff, Whr,
                                                  deg, n4);
    k_hist<<<(E + 1023) / 1024, NTHR, 0, stream>>>(ei, deg, perm, E);
    k_proj<<<(n + 31) / 32, NTHR, 0, stream>>>(x, Whr, att_src, att_dst, xph,
                                               s_src, s_dst, n);
    scan_kernel<<<1, SCAN_T, 0, stream>>>(deg, rowptr, n);
    edge_kernel<<<(EP + NTHR - 1) / NTHR, NTHR, 0, stream>>>(ei, ea, s_src, s_dst, weff,
                                                             rowptr, perm, rec, E, n);
    agg_kernel<<<(n + 3) / 4, NTHR, 0, stream>>>(rowptr, rec, xph, bias, out, n);
}

// Round 19
// 89.934 us; speedup vs baseline: 1.3415x; 1.0422x over previous
//
#include <hip/hip_runtime.h>
#include <math.h>

#define IN_DIM 256
#define HD 256
#define EDGE_DIM 32
#define NEG_SLOPE 0.2f
#define NTHR 256
#define WCVT_VBS 32

typedef _Float16 f16x8 __attribute__((ext_vector_type(8)));
typedef _Float16 f16x4 __attribute__((ext_vector_type(4)));
typedef float f32x4 __attribute__((ext_vector_type(4)));

__device__ __forceinline__ f16x8 cvt8(const float* p) {
    float4 lo = *(const float4*)p;
    float4 hi = *(const float4*)(p + 4);
    auto a = __builtin_amdgcn_cvt_pkrtz(lo.x, lo.y);
    auto b = __builtin_amdgcn_cvt_pkrtz(lo.z, lo.w);
    auto c = __builtin_amdgcn_cvt_pkrtz(hi.x, hi.y);
    auto d = __builtin_amdgcn_cvt_pkrtz(hi.z, hi.w);
    f16x8 r;
    r[0] = (_Float16)a[0]; r[1] = (_Float16)a[1];
    r[2] = (_Float16)b[0]; r[3] = (_Float16)b[1];
    r[4] = (_Float16)c[0]; r[5] = (_Float16)c[1];
    r[6] = (_Float16)d[0]; r[7] = (_Float16)d[1];
    return r;
}

// pack two floats as bf16 pair (round-to-nearest-even); bf16 keeps fp32 range -> no overflow
__device__ __forceinline__ int pack_bf16x2(float a, float b) {
    unsigned ua = __builtin_bit_cast(unsigned, a);
    unsigned ub = __builtin_bit_cast(unsigned, b);
    ua = (ua + 0x7fffu + ((ua >> 16) & 1u)) >> 16;
    ub = (ub + 0x7fffu + ((ub >> 16) & 1u)) >> 16;
    return (int)(ua | (ub << 16));
}

// per-block int64-vs-int32 detect: high words of int64 node ids are all zero
__device__ __forceinline__ int detect64(const int* __restrict__ ei) {
    __shared__ int anynz;
    if (threadIdx.x == 0) anynz = 0;
    __syncthreads();
    if (ei[2 * threadIdx.x + 1] != 0) atomicOr(&anynz, 1);
    __syncthreads();
    return anynz == 0;
}

__device__ __forceinline__ void load_edge(const int* ei, int e, int E, int n, int is64,
                                          int& s, int& d) {
    if (e < E) {
        if (is64) { s = ei[2 * e]; d = ei[2 * E + 2 * e]; }
        else      { s = ei[e];     d = ei[E + e]; }
    } else {
        s = d = e - E;  // self loop
    }
}

// ---------- k_pre: weff (b0) | W->fp16 k-major repack (b1..32) | zero deg (b33..) ----------
__global__ __launch_bounds__(NTHR) void k_pre(const float* __restrict__ lew,
                                              const float* __restrict__ ae,
                                              const float* __restrict__ W,
                                              float* __restrict__ weff,
                                              _Float16* __restrict__ Whr,
                                              int* __restrict__ deg, int n4) {
    int b = blockIdx.x;
    int t = threadIdx.x;
    if (b == 0) {
        if (t < 128) {
            int h = t >> 5, k = t & 31;
            float s = 0.f;
#pragma unroll 8
            for (int d = 0; d < 64; ++d) s += lew[(h * 64 + d) * 32 + k] * ae[h * 64 + d];
            weff[t] = s;
        }
    } else if (b <= WCVT_VBS) {
        int idx = (b - 1) * 2048 + t * 8;   // element index into row-major W (col*256+k)
        int col = idx >> 8;
        int k = idx & 255;                  // 8 consecutive k
        f16x8 v = cvt8(&W[idx]);
        *(f16x8*)&Whr[(size_t)(k >> 3) * 2048 + col * 8] = v;
    } else {
        int i = (b - 1 - WCVT_VBS) * 1024 + t * 4;
        if (i < n4) *(int4*)&deg[i] = make_int4(0, 0, 0, 0);
    }
}

// ---------- k_hist: global-atomic degree histogram + perm (4 edges/thread) ----------
__global__ __launch_bounds__(NTHR) void k_hist(const int* __restrict__ ei,
                                               int* __restrict__ deg,
                                               int* __restrict__ perm, int E) {
    int is64 = detect64(ei);
    int e0 = (blockIdx.x * NTHR + threadIdx.x) * 4;
    if (e0 >= E) return;
    if (e0 + 4 <= E) {
        int4 pm;
        if (!is64) {
            int4 d4 = *(const int4*)&ei[E + e0];
            pm.x = atomicAdd(&deg[d4.x], 1);
            pm.y = atomicAdd(&deg[d4.y], 1);
            pm.z = atomicAdd(&deg[d4.z], 1);
            pm.w = atomicAdd(&deg[d4.w], 1);
        } else {
            int4 a = *(const int4*)&ei[2 * E + 2 * e0];
            int4 b4 = *(const int4*)&ei[2 * E + 2 * e0 + 4];
            pm.x = atomicAdd(&deg[a.x], 1);
            pm.y = atomicAdd(&deg[a.z], 1);
            pm.z = atomicAdd(&deg[b4.x], 1);
            pm.w = atomicAdd(&deg[b4.z], 1);
        }
        *(int4*)&perm[e0] = pm;
    } else {
        for (int e = e0; e < E && e < e0 + 4; ++e) {
            int d = is64 ? ei[2 * E + 2 * e] : ei[E + e];
            perm[e] = atomicAdd(&deg[d], 1);
        }
    }
}

// ---------- k_proj: 32 rows/block; x staged in LDS (f16, k-major planes); Whr coalesced ----
#define XPLN 33
__global__ __launch_bounds__(NTHR) void k_proj(const float* __restrict__ x,
                                               const _Float16* __restrict__ Whr,
                                               const float* __restrict__ asrc_g,
                                               const float* __restrict__ adst_g,
                                               _Float16* __restrict__ xph,
                                               float* __restrict__ s_src,
                                               float* __restrict__ s_dst, int n) {
    __shared__ _Float16 xs[32 * XPLN * 8];   // 16.9 KB
    int t = threadIdx.x;
    int lane = t & 63;
    int w = t >> 6;              // wave id == head id (col group)
    int m0 = blockIdx.x * 32;
    int c0 = w * 64;
    int r = lane & 15;
    int kq = lane >> 4;          // 0..3

    // ---- stage 32 x-rows -> LDS f16 (coalesced 128B per thread) ----
    {
        int rr = t >> 3;               // 0..31
        int kc = (t & 7) * 32;         // 0..224
        int grow = m0 + rr;
        if (grow < n) {
            const float* xp = &x[(size_t)grow * IN_DIM + kc];
#pragma unroll
            for (int c4 = 0; c4 < 4; ++c4) {
                f16x8 v = cvt8(xp + c4 * 8);
                *(f16x8*)&xs[(size_t)((kc >> 3) + c4) * (XPLN * 8) + rr * 8] = v;
            }
        } else {
            f16x8 z = {0, 0, 0, 0, 0, 0, 0, 0};
#pragma unroll
            for (int c4 = 0; c4 < 4; ++c4)
                *(f16x8*)&xs[(size_t)((kc >> 3) + c4) * (XPLN * 8) + rr * 8] = z;
        }
    }

    float asr[4], ads[4];
#pragma unroll
    for (int ci = 0; ci < 4; ++ci) {
        asr[ci] = asrc_g[c0 + ci * 16 + r];
        ads[ci] = adst_g[c0 + ci * 16 + r];
    }

    f32x4 acc[2][4];
#pragma unroll
    for (int mi = 0; mi < 2; ++mi)
#pragma unroll
        for (int j = 0; j < 4; ++j) acc[mi][j] = (f32x4){0.f, 0.f, 0.f, 0.f};

    __syncthreads();

#pragma unroll
    for (int k0 = 0; k0 < IN_DIM; k0 += 32) {
        int p = (k0 >> 3) + kq;
        f16x8 a0 = *(const f16x8*)&xs[(size_t)p * (XPLN * 8) + (0 * 16 + r) * 8];
        f16x8 a1 = *(const f16x8*)&xs[(size_t)p * (XPLN * 8) + (1 * 16 + r) * 8];
        f16x8 bfr[4];
#pragma unroll
        for (int ci = 0; ci < 4; ++ci)
            bfr[ci] = *(const f16x8*)&Whr[(size_t)p * 2048 + (c0 + ci * 16 + r) * 8];
#pragma unroll
        for (int ci = 0; ci < 4; ++ci) {
            acc[0][ci] = __builtin_amdgcn_mfma_f32_16x16x32_f16(a0, bfr[ci], acc[0][ci],
                                                                0, 0, 0);
            acc[1][ci] = __builtin_amdgcn_mfma_f32_16x16x32_f16(a1, bfr[ci], acc[1][ci],
                                                                0, 0, 0);
        }
    }
    // C/D layout: col = lane&15, row = (lane>>4)*4 + j
#pragma unroll
    for (int mi = 0; mi < 2; ++mi) {
#pragma unroll
        for (int j = 0; j < 4; ++j) {
            int orow = m0 + mi * 16 + kq * 4 + j;
            if (orow < n) {
#pragma unroll
                for (int ci = 0; ci < 4; ++ci)
                    xph[(size_t)orow * HD + c0 + ci * 16 + r] = (_Float16)acc[mi][ci][j];
            }
        }
    }
    // fused attention scores: wave w == head w owns cols [w*64, w*64+64)
#pragma unroll
    for (int mi = 0; mi < 2; ++mi) {
#pragma unroll
        for (int j = 0; j < 4; ++j) {
            float vs = 0.f, vd = 0.f;
#pragma unroll
            for (int ci = 0; ci < 4; ++ci) {
                vs += acc[mi][ci][j] * asr[ci];
                vd += acc[mi][ci][j] * ads[ci];
            }
#pragma unroll
            for (int msk = 1; msk < 16; msk <<= 1) {
                vs += __shfl_xor(vs, msk);
                vd += __shfl_xor(vd, msk);
            }
            int orow = m0 + mi * 16 + kq * 4 + j;
            if (r == 0 && orow < n) {
                s_src[orow * 4 + w] = vs;
                s_dst[orow * 4 + w] = vd;
            }
        }
    }
}

// ---------- single-block exclusive scan over (deg+1), int4-vectorized ----------
#define SCAN_T 1024
__global__ __launch_bounds__(SCAN_T) void scan_kernel(const int* __restrict__ deg,
                                                      int* __restrict__ rowptr, int n) {
    __shared__ int sdata[SCAN_T];
    int t = threadIdx.x;
    int per = (n + SCAN_T - 1) / SCAN_T;
    int begin = t * per;
    int endi = begin + per;
    if (endi > n) endi = n;
    if (begin > n) begin = n;
    bool vec = ((begin & 3) == 0) && (((endi - begin) & 3) == 0);
    int s = 0;
    if (vec) {
        for (int i = begin; i < endi; i += 4) {
            int4 v = *(const int4*)&deg[i];
            s += v.x + v.y + v.z + v.w + 4;
        }
    } else {
        for (int i = begin; i < endi; ++i) s += deg[i] + 1;
    }
    sdata[t] = s;
    __syncthreads();
    for (int off = 1; off < SCAN_T; off <<= 1) {
        int v = 0;
        if (t >= off) v = sdata[t - off];
        __syncthreads();
        sdata[t] += v;
        __syncthreads();
    }
    int run = (t == 0) ? 0 : sdata[t - 1];
    if (vec) {
        for (int i = begin; i < endi; i += 4) {
            int4 v = *(const int4*)&deg[i];
            int4 o;
            o.x = run; run += v.x + 1;
            o.y = run; run += v.y + 1;
            o.z = run; run += v.z + 1;
            o.w = run; run += v.w + 1;
            *(int4*)&rowptr[i] = o;
        }
    } else {
        for (int i = begin; i < endi; ++i) {
            rowptr[i] = run;
            run += deg[i] + 1;
        }
    }
    if (t == SCAN_T - 1) rowptr[n] = run;
}

// ---------- edge scoring + exp + CSR placement; packed 16B record ----------
// rec[pos] (int4): .x = src, .y = 0, .z = bf16x2(p0,p1), .w = bf16x2(p2,p3)
__global__ __launch_bounds__(NTHR) void edge_kernel(const int* __restrict__ ei,
                                                    const float* __restrict__ ea,
                                                    const float* __restrict__ s_src,
                                                    const float* __restrict__ s_dst,
                                                    const float* __restrict__ weff,
                                                    const int* __restrict__ rowptr,
                                                    const int* __restrict__ perm,
                                                    int4* __restrict__ rec,
                                                    int E, int n) {
    int is64 = detect64(ei);
    __shared__ float we[128];
    if (threadIdx.x < 128) we[threadIdx.x] = weff[threadIdx.x];
    __syncthreads();
    int e = blockIdx.x * blockDim.x + threadIdx.x;
    int EP = E + n;
    if (e >= EP) return;
    int s, d;
    load_edge(ei, e, E, n, is64, s, d);
    int pos;
    if (e < E) pos = rowptr[d] + perm[e];
    else       pos = rowptr[d + 1] - 1;   // self-loop takes last slot of bucket
    float4 vs = *(const float4*)&s_src[(size_t)s * 4];
    float4 vd = *(const float4*)&s_dst[(size_t)d * 4];
    float ed[4] = {0.f, 0.f, 0.f, 0.f};
    if (e < E) {
#pragma unroll
        for (int k = 0; k < EDGE_DIM; k += 4) {
            float4 v = *(const float4*)&ea[(size_t)e * EDGE_DIM + k];
#pragma unroll
            for (int h = 0; h < 4; ++h) {
                ed[h] += v.x * we[h * 32 + k + 0] + v.y * we[h * 32 + k + 1] +
                         v.z * we[h * 32 + k + 2] + v.w * we[h * 32 + k + 3];
            }
        }
    }
    float t0 = vs.x + vd.x + ed[0];
    float t1 = vs.y + vd.y + ed[1];
    float t2 = vs.z + vd.z + ed[2];
    float t3 = vs.w + vd.w + ed[3];
    t0 = t0 >= 0.f ? t0 : NEG_SLOPE * t0;
    t1 = t1 >= 0.f ? t1 : NEG_SLOPE * t1;
    t2 = t2 >= 0.f ? t2 : NEG_SLOPE * t2;
    t3 = t3 >= 0.f ? t3 : NEG_SLOPE * t3;
    int4 r4;
    r4.x = s;
    r4.y = 0;
    r4.z = pack_bf16x2(__expf(t0), __expf(t1));
    r4.w = pack_bf16x2(__expf(t2), __expf(t3));
    rec[pos] = r4;
}

// ---------- aggregation v3: wave/node, half-wave/edge, LDS record staging (bf16 p) ----------
#define AGG_CAP 64
__device__ __forceinline__ float rec_p(const int4& r, int h) {
    unsigned u = (unsigned)((h < 2) ? r.z : r.w);
    unsigned bits = (h & 1) ? (u & 0xffff0000u) : (u << 16);
    return __builtin_bit_cast(float, bits);
}
__global__ __launch_bounds__(NTHR) void agg_kernel(const int* __restrict__ rowptr,
                                                   const int4* __restrict__ rec,
                                                   const _Float16* __restrict__ xph,
                                                   const float* __restrict__ bias,
                                                   float* __restrict__ out, int n) {
    __shared__ int4 rl[4][AGG_CAP];
    int wv = threadIdx.x >> 6;
    int wid = (blockIdx.x * NTHR + threadIdx.x) >> 6;
    int lane = threadIdx.x & 63;
    int start = 0, end = 0, deg = 0;
    if (wid < n) {
        start = rowptr[wid];
        end = rowptr[wid + 1];
        deg = end - start;
        if (lane < deg && lane < AGG_CAP) rl[wv][lane] = rec[start + lane];
    }
    __syncthreads();
    if (wid >= n) return;
    int sub = lane >> 5;     // which edge of the pair
    int l = lane & 31;       // dim group: dims [8l, 8l+8)
    int h = l >> 3;          // head

    float dh = 0.f;
    float acc[8];
#pragma unroll
    for (int k = 0; k < 8; ++k) acc[k] = 0.f;

    int stop = deg < AGG_CAP ? deg : AGG_CAP;
    int idx = sub;
    while (idx + 2 < stop) {
        int4 r0 = rl[wv][idx];
        int4 r1 = rl[wv][idx + 2];
        float p0 = rec_p(r0, h);
        float p1 = rec_p(r1, h);
        f16x8 x0 = *(const f16x8*)&xph[(size_t)r0.x * HD + l * 8];
        f16x8 x1 = *(const f16x8*)&xph[(size_t)r1.x * HD + l * 8];
        dh += p0 + p1;
#pragma unroll
        for (int k = 0; k < 8; ++k)
            acc[k] += p0 * (float)x0[k] + p1 * (float)x1[k];
        idx += 4;
    }
    if (idx < stop) {
        int4 r0 = rl[wv][idx];
        float p0 = rec_p(r0, h);
        f16x8 x0 = *(const f16x8*)&xph[(size_t)r0.x * HD + l * 8];
        dh += p0;
#pragma unroll
        for (int k = 0; k < 8; ++k) acc[k] += p0 * (float)x0[k];
    }
    // rare: deg > AGG_CAP tail from global
    for (int j = AGG_CAP + sub; j < deg; j += 2) {
        int4 r0 = rec[start + j];
        float p0 = rec_p(r0, h);
        f16x8 x0 = *(const f16x8*)&xph[(size_t)r0.x * HD + l * 8];
        dh += p0;
#pragma unroll
        for (int k = 0; k < 8; ++k) acc[k] += p0 * (float)x0[k];
    }
    // combine the two halves
    dh += __shfl_xor(dh, 32);
#pragma unroll
    for (int k = 0; k < 8; ++k) acc[k] += __shfl_xor(acc[k], 32);
    float invh = 1.f / (dh + 1e-12f);
    // lane l (sub=0) writes dims [8l, 8l+4); lane l+32 writes [8l+4, 8l+8)
    float a0 = sub ? acc[4] : acc[0];
    float a1 = sub ? acc[5] : acc[1];
    float a2 = sub ? acc[6] : acc[2];
    float a3 = sub ? acc[7] : acc[3];
    int doff = l * 8 + sub * 4;
    float4 b = *(const float4*)&bias[doff];
    float4 o4;
    o4.x = a0 * invh + b.x;
    o4.y = a1 * invh + b.y;
    o4.z = a2 * invh + b.z;
    o4.w = a3 * invh + b.w;
    *(float4*)&out[(size_t)wid * HD + doff] = o4;
}

extern "C" void kernel_launch(void* const* d_in, const int* in_sizes, int n_in,
                              void* d_out, int out_size, void* d_ws, size_t ws_size,
                              hipStream_t stream) {
    const float* x        = (const float*)d_in[0];
    const int*   ei       = (const int*)d_in[1];
    const float* ea       = (const float*)d_in[2];
    const float* lin_W    = (const float*)d_in[3];
    const float* att_src  = (const float*)d_in[4];
    const float* att_dst  = (const float*)d_in[5];
    const float* lin_eW   = (const float*)d_in[6];
    const float* att_edge = (const float*)d_in[7];
    const float* bias     = (const float*)d_in[8];
    float* out = (float*)d_out;

    int n  = in_sizes[0] / IN_DIM;     // 20000
    int E  = in_sizes[2] / EDGE_DIM;   // 320000
    int EP = E + n;

    char* p = (char*)d_ws;
    auto alloc = [&](size_t bytes) {
        char* r = p;
        p += (bytes + 255) & ~(size_t)255;
        return r;
    };
    _Float16* xph   = (_Float16*)alloc((size_t)n * HD * 2);
    _Float16* Whr   = (_Float16*)alloc((size_t)HD * IN_DIM * 2);
    float* s_src    = (float*)alloc((size_t)n * 4 * 4);
    float* s_dst    = (float*)alloc((size_t)n * 4 * 4);
    int4*  rec      = (int4*)alloc((size_t)EP * 16);
    float* weff     = (float*)alloc(128 * 4);
    int*   deg      = (int*)alloc((size_t)(n + 4) * 4);
    int*   rowptr   = (int*)alloc((size_t)(n + 1) * 4);
    int*   perm     = (int*)alloc((size_t)E * 4);

    int n4 = (n + 3) & ~3;
    int ZV = (n4 + 1023) / 1024;

    k_pre<<<1 + WCVT_VBS + ZV, NTHR, 0, stream>>>(lin_eW, att_edge, lin_W, weff, Whr,
                                                  deg, n4);
    k_hist<<<(E + 1023) / 1024, NTHR, 0, stream>>>(ei, deg, perm, E);
    k_proj<<<(n + 31) / 32, NTHR, 0, stream>>>(x, Whr, att_src, att_dst, xph,
                                               s_src, s_dst, n);
    scan_kernel<<<1, SCAN_T, 0, stream>>>(deg, rowptr, n);
    edge_kernel<<<(EP + NTHR - 1) / NTHR, NTHR, 0, stream>>>(ei, ea, s_src, s_dst, weff,
                                                             rowptr, perm, rec, E, n);
    agg_kernel<<<(n + 3) / 4, NTHR, 0, stream>>>(rowptr, rec, xph, bias, out, n);
}

// Round 20
// 84.011 us; speedup vs baseline: 1.4360x; 1.0705x over previous
//
#include <hip/hip_runtime.h>
#include <math.h>

#define IN_DIM 256
#define HD 256
#define EDGE_DIM 32
#define NEG_SLOPE 0.2f
#define NTHR 256
#define WCVT_VBS 32

typedef _Float16 f16x8 __attribute__((ext_vector_type(8)));
typedef _Float16 f16x4 __attribute__((ext_vector_type(4)));
typedef float f32x4 __attribute__((ext_vector_type(4)));

__device__ __forceinline__ f16x8 cvt8(const float* p) {
    float4 lo = *(const float4*)p;
    float4 hi = *(const float4*)(p + 4);
    auto a = __builtin_amdgcn_cvt_pkrtz(lo.x, lo.y);
    auto b = __builtin_amdgcn_cvt_pkrtz(lo.z, lo.w);
    auto c = __builtin_amdgcn_cvt_pkrtz(hi.x, hi.y);
    auto d = __builtin_amdgcn_cvt_pkrtz(hi.z, hi.w);
    f16x8 r;
    r[0] = (_Float16)a[0]; r[1] = (_Float16)a[1];
    r[2] = (_Float16)b[0]; r[3] = (_Float16)b[1];
    r[4] = (_Float16)c[0]; r[5] = (_Float16)c[1];
    r[6] = (_Float16)d[0]; r[7] = (_Float16)d[1];
    return r;
}

// pack two floats as bf16 pair (round-to-nearest-even); bf16 keeps fp32 range -> no overflow
__device__ __forceinline__ int pack_bf16x2(float a, float b) {
    unsigned ua = __builtin_bit_cast(unsigned, a);
    unsigned ub = __builtin_bit_cast(unsigned, b);
    ua = (ua + 0x7fffu + ((ua >> 16) & 1u)) >> 16;
    ub = (ub + 0x7fffu + ((ub >> 16) & 1u)) >> 16;
    return (int)(ua | (ub << 16));
}

// per-block int64-vs-int32 detect: high words of int64 node ids are all zero
__device__ __forceinline__ int detect64(const int* __restrict__ ei) {
    __shared__ int anynz;
    if (threadIdx.x == 0) anynz = 0;
    __syncthreads();
    if (ei[2 * threadIdx.x + 1] != 0) atomicOr(&anynz, 1);
    __syncthreads();
    return anynz == 0;
}

__device__ __forceinline__ void load_edge(const int* ei, int e, int E, int n, int is64,
                                          int& s, int& d) {
    if (e < E) {
        if (is64) { s = ei[2 * e]; d = ei[2 * E + 2 * e]; }
        else      { s = ei[e];     d = ei[E + e]; }
    } else {
        s = d = e - E;  // self loop
    }
}

// ---------- k_pre: weff (b0) | W->fp16 k-major repack (b1..32) | zero deg (b33..) ----------
__global__ __launch_bounds__(NTHR) void k_pre(const float* __restrict__ lew,
                                              const float* __restrict__ ae,
                                              const float* __restrict__ W,
                                              float* __restrict__ weff,
                                              _Float16* __restrict__ Whr,
                                              int* __restrict__ deg, int n4) {
    int b = blockIdx.x;
    int t = threadIdx.x;
    if (b == 0) {
        if (t < 128) {
            int h = t >> 5, k = t & 31;
            float s = 0.f;
#pragma unroll 8
            for (int d = 0; d < 64; ++d) s += lew[(h * 64 + d) * 32 + k] * ae[h * 64 + d];
            weff[t] = s;
        }
    } else if (b <= WCVT_VBS) {
        int idx = (b - 1) * 2048 + t * 8;   // element index into row-major W (col*256+k)
        int col = idx >> 8;
        int k = idx & 255;                  // 8 consecutive k
        f16x8 v = cvt8(&W[idx]);
        *(f16x8*)&Whr[(size_t)(k >> 3) * 2048 + col * 8] = v;
    } else {
        int i = (b - 1 - WCVT_VBS) * 1024 + t * 4;
        if (i < n4) *(int4*)&deg[i] = make_int4(0, 0, 0, 0);
    }
}

// ---------- k_mid: hist blocks (b<histv) || proj blocks (b>=histv) ----------
// hist: global-atomic degree histogram + perm (4 edges/thread) — latency-bound,
// overlaps with proj's BW/MFMA-bound blocks on the same CUs.
#define XPLN 33
__global__ __launch_bounds__(NTHR) void k_mid(const int* __restrict__ ei,
                                              const float* __restrict__ x,
                                              const _Float16* __restrict__ Whr,
                                              const float* __restrict__ asrc_g,
                                              const float* __restrict__ adst_g,
                                              _Float16* __restrict__ xph,
                                              float* __restrict__ s_src,
                                              float* __restrict__ s_dst,
                                              int* __restrict__ deg,
                                              int* __restrict__ perm,
                                              int histv, int E, int n) {
    __shared__ _Float16 xs[32 * XPLN * 8];   // 16.9 KB (proj branch)
    int b = blockIdx.x;
    int t = threadIdx.x;
    if (b < histv) {
        int is64 = detect64(ei);
        int e0 = (b * NTHR + t) * 4;
        if (e0 >= E) return;
        if (e0 + 4 <= E) {
            int4 pm;
            if (!is64) {
                int4 d4 = *(const int4*)&ei[E + e0];
                pm.x = atomicAdd(&deg[d4.x], 1);
                pm.y = atomicAdd(&deg[d4.y], 1);
                pm.z = atomicAdd(&deg[d4.z], 1);
                pm.w = atomicAdd(&deg[d4.w], 1);
            } else {
                int4 a = *(const int4*)&ei[2 * E + 2 * e0];
                int4 b4 = *(const int4*)&ei[2 * E + 2 * e0 + 4];
                pm.x = atomicAdd(&deg[a.x], 1);
                pm.y = atomicAdd(&deg[a.z], 1);
                pm.z = atomicAdd(&deg[b4.x], 1);
                pm.w = atomicAdd(&deg[b4.z], 1);
            }
            *(int4*)&perm[e0] = pm;
        } else {
            for (int e = e0; e < E && e < e0 + 4; ++e) {
                int d = is64 ? ei[2 * E + 2 * e] : ei[E + e];
                perm[e] = atomicAdd(&deg[d], 1);
            }
        }
        return;
    }
    // ----- proj: 32 rows/block; x staged in LDS; Whr k-major coalesced -----
    int vb = b - histv;
    int lane = t & 63;
    int w = t >> 6;              // wave id == head id (col group)
    int m0 = vb * 32;
    int c0 = w * 64;
    int r = lane & 15;
    int kq = lane >> 4;          // 0..3

    // ---- stage 32 x-rows -> LDS f16 (coalesced 128B per thread) ----
    {
        int rr = t >> 3;               // 0..31
        int kc = (t & 7) * 32;         // 0..224
        int grow = m0 + rr;
        if (grow < n) {
            const float* xp = &x[(size_t)grow * IN_DIM + kc];
#pragma unroll
            for (int c4 = 0; c4 < 4; ++c4) {
                f16x8 v = cvt8(xp + c4 * 8);
                *(f16x8*)&xs[(size_t)((kc >> 3) + c4) * (XPLN * 8) + rr * 8] = v;
            }
        } else {
            f16x8 z = {0, 0, 0, 0, 0, 0, 0, 0};
#pragma unroll
            for (int c4 = 0; c4 < 4; ++c4)
                *(f16x8*)&xs[(size_t)((kc >> 3) + c4) * (XPLN * 8) + rr * 8] = z;
        }
    }

    float asr[4], ads[4];
#pragma unroll
    for (int ci = 0; ci < 4; ++ci) {
        asr[ci] = asrc_g[c0 + ci * 16 + r];
        ads[ci] = adst_g[c0 + ci * 16 + r];
    }

    f32x4 acc[2][4];
#pragma unroll
    for (int mi = 0; mi < 2; ++mi)
#pragma unroll
        for (int j = 0; j < 4; ++j) acc[mi][j] = (f32x4){0.f, 0.f, 0.f, 0.f};

    __syncthreads();

#pragma unroll
    for (int k0 = 0; k0 < IN_DIM; k0 += 32) {
        int p = (k0 >> 3) + kq;
        f16x8 a0 = *(const f16x8*)&xs[(size_t)p * (XPLN * 8) + (0 * 16 + r) * 8];
        f16x8 a1 = *(const f16x8*)&xs[(size_t)p * (XPLN * 8) + (1 * 16 + r) * 8];
        f16x8 bfr[4];
#pragma unroll
        for (int ci = 0; ci < 4; ++ci)
            bfr[ci] = *(const f16x8*)&Whr[(size_t)p * 2048 + (c0 + ci * 16 + r) * 8];
#pragma unroll
        for (int ci = 0; ci < 4; ++ci) {
            acc[0][ci] = __builtin_amdgcn_mfma_f32_16x16x32_f16(a0, bfr[ci], acc[0][ci],
                                                                0, 0, 0);
            acc[1][ci] = __builtin_amdgcn_mfma_f32_16x16x32_f16(a1, bfr[ci], acc[1][ci],
                                                                0, 0, 0);
        }
    }
    // C/D layout: col = lane&15, row = (lane>>4)*4 + j
#pragma unroll
    for (int mi = 0; mi < 2; ++mi) {
#pragma unroll
        for (int j = 0; j < 4; ++j) {
            int orow = m0 + mi * 16 + kq * 4 + j;
            if (orow < n) {
#pragma unroll
                for (int ci = 0; ci < 4; ++ci)
                    xph[(size_t)orow * HD + c0 + ci * 16 + r] = (_Float16)acc[mi][ci][j];
            }
        }
    }
    // fused attention scores: wave w == head w owns cols [w*64, w*64+64)
#pragma unroll
    for (int mi = 0; mi < 2; ++mi) {
#pragma unroll
        for (int j = 0; j < 4; ++j) {
            float vs = 0.f, vd = 0.f;
#pragma unroll
            for (int ci = 0; ci < 4; ++ci) {
                vs += acc[mi][ci][j] * asr[ci];
                vd += acc[mi][ci][j] * ads[ci];
            }
#pragma unroll
            for (int msk = 1; msk < 16; msk <<= 1) {
                vs += __shfl_xor(vs, msk);
                vd += __shfl_xor(vd, msk);
            }
            int orow = m0 + mi * 16 + kq * 4 + j;
            if (r == 0 && orow < n) {
                s_src[orow * 4 + w] = vs;
                s_dst[orow * 4 + w] = vd;
            }
        }
    }
}

// ---------- single-block exclusive scan over (deg+1), int4-vectorized ----------
#define SCAN_T 1024
__global__ __launch_bounds__(SCAN_T) void scan_kernel(const int* __restrict__ deg,
                                                      int* __restrict__ rowptr, int n) {
    __shared__ int sdata[SCAN_T];
    int t = threadIdx.x;
    int per = (n + SCAN_T - 1) / SCAN_T;
    int begin = t * per;
    int endi = begin + per;
    if (endi > n) endi = n;
    if (begin > n) begin = n;
    bool vec = ((begin & 3) == 0) && (((endi - begin) & 3) == 0);
    int s = 0;
    if (vec) {
        for (int i = begin; i < endi; i += 4) {
            int4 v = *(const int4*)&deg[i];
            s += v.x + v.y + v.z + v.w + 4;
        }
    } else {
        for (int i = begin; i < endi; ++i) s += deg[i] + 1;
    }
    sdata[t] = s;
    __syncthreads();
    for (int off = 1; off < SCAN_T; off <<= 1) {
        int v = 0;
        if (t >= off) v = sdata[t - off];
        __syncthreads();
        sdata[t] += v;
        __syncthreads();
    }
    int run = (t == 0) ? 0 : sdata[t - 1];
    if (vec) {
        for (int i = begin; i < endi; i += 4) {
            int4 v = *(const int4*)&deg[i];
            int4 o;
            o.x = run; run += v.x + 1;
            o.y = run; run += v.y + 1;
            o.z = run; run += v.z + 1;
            o.w = run; run += v.w + 1;
            *(int4*)&rowptr[i] = o;
        }
    } else {
        for (int i = begin; i < endi; ++i) {
            rowptr[i] = run;
            run += deg[i] + 1;
        }
    }
    if (t == SCAN_T - 1) rowptr[n] = run;
}

// ---------- edge scoring + exp + CSR placement; packed 16B record ----------
// rec[pos] (int4): .x = src, .y = 0, .z = bf16x2(p0,p1), .w = bf16x2(p2,p3)
__global__ __launch_bounds__(NTHR) void edge_kernel(const int* __restrict__ ei,
                                                    const float* __restrict__ ea,
                                                    const float* __restrict__ s_src,
                                                    const float* __restrict__ s_dst,
                                                    const float* __restrict__ weff,
                                                    const int* __restrict__ rowptr,
                                                    const int* __restrict__ perm,
                                                    int4* __restrict__ rec,
                                                    int E, int n) {
    int is64 = detect64(ei);
    __shared__ float we[128];
    if (threadIdx.x < 128) we[threadIdx.x] = weff[threadIdx.x];
    __syncthreads();
    int e = blockIdx.x * blockDim.x + threadIdx.x;
    int EP = E + n;
    if (e >= EP) return;
    int s, d;
    load_edge(ei, e, E, n, is64, s, d);
    int pos;
    if (e < E) pos = rowptr[d] + perm[e];
    else       pos = rowptr[d + 1] - 1;   // self-loop takes last slot of bucket
    float4 vs = *(const float4*)&s_src[(size_t)s * 4];
    float4 vd = *(const float4*)&s_dst[(size_t)d * 4];
    float ed[4] = {0.f, 0.f, 0.f, 0.f};
    if (e < E) {
#pragma unroll
        for (int k = 0; k < EDGE_DIM; k += 4) {
            float4 v = *(const float4*)&ea[(size_t)e * EDGE_DIM + k];
#pragma unroll
            for (int h = 0; h < 4; ++h) {
                ed[h] += v.x * we[h * 32 + k + 0] + v.y * we[h * 32 + k + 1] +
                         v.z * we[h * 32 + k + 2] + v.w * we[h * 32 + k + 3];
            }
        }
    }
    float t0 = vs.x + vd.x + ed[0];
    float t1 = vs.y + vd.y + ed[1];
    float t2 = vs.z + vd.z + ed[2];
    float t3 = vs.w + vd.w + ed[3];
    t0 = t0 >= 0.f ? t0 : NEG_SLOPE * t0;
    t1 = t1 >= 0.f ? t1 : NEG_SLOPE * t1;
    t2 = t2 >= 0.f ? t2 : NEG_SLOPE * t2;
    t3 = t3 >= 0.f ? t3 : NEG_SLOPE * t3;
    int4 r4;
    r4.x = s;
    r4.y = 0;
    r4.z = pack_bf16x2(__expf(t0), __expf(t1));
    r4.w = pack_bf16x2(__expf(t2), __expf(t3));
    rec[pos] = r4;
}

// ---------- aggregation: wave/node, half-wave/edge, LDS record staging (bf16 p) ----------
#define AGG_CAP 64
__device__ __forceinline__ float rec_p(const int4& r, int h) {
    unsigned u = (unsigned)((h < 2) ? r.z : r.w);
    unsigned bits = (h & 1) ? (u & 0xffff0000u) : (u << 16);
    return __builtin_bit_cast(float, bits);
}
__global__ __launch_bounds__(NTHR) void agg_kernel(const int* __restrict__ rowptr,
                                                   const int4* __restrict__ rec,
                                                   const _Float16* __restrict__ xph,
                                                   const float* __restrict__ bias,
                                                   float* __restrict__ out, int n) {
    __shared__ int4 rl[4][AGG_CAP];
    int wv = threadIdx.x >> 6;
    int wid = (blockIdx.x * NTHR + threadIdx.x) >> 6;
    int lane = threadIdx.x & 63;
    int start = 0, end = 0, deg = 0;
    if (wid < n) {
        start = rowptr[wid];
        end = rowptr[wid + 1];
        deg = end - start;
        if (lane < deg && lane < AGG_CAP) rl[wv][lane] = rec[start + lane];
    }
    __syncthreads();
    if (wid >= n) return;
    int sub = lane >> 5;     // which edge of the pair
    int l = lane & 31;       // dim group: dims [8l, 8l+8)
    int h = l >> 3;          // head

    float dh = 0.f;
    float acc[8];
#pragma unroll
    for (int k = 0; k < 8; ++k) acc[k] = 0.f;

    int stop = deg < AGG_CAP ? deg : AGG_CAP;
    int idx = sub;
    while (idx + 2 < stop) {
        int4 r0 = rl[wv][idx];
        int4 r1 = rl[wv][idx + 2];
        float p0 = rec_p(r0, h);
        float p1 = rec_p(r1, h);
        f16x8 x0 = *(const f16x8*)&xph[(size_t)r0.x * HD + l * 8];
        f16x8 x1 = *(const f16x8*)&xph[(size_t)r1.x * HD + l * 8];
        dh += p0 + p1;
#pragma unroll
        for (int k = 0; k < 8; ++k)
            acc[k] += p0 * (float)x0[k] + p1 * (float)x1[k];
        idx += 4;
    }
    if (idx < stop) {
        int4 r0 = rl[wv][idx];
        float p0 = rec_p(r0, h);
        f16x8 x0 = *(const f16x8*)&xph[(size_t)r0.x * HD + l * 8];
        dh += p0;
#pragma unroll
        for (int k = 0; k < 8; ++k) acc[k] += p0 * (float)x0[k];
    }
    // rare: deg > AGG_CAP tail from global
    for (int j = AGG_CAP + sub; j < deg; j += 2) {
        int4 r0 = rec[start + j];
        float p0 = rec_p(r0, h);
        f16x8 x0 = *(const f16x8*)&xph[(size_t)r0.x * HD + l * 8];
        dh += p0;
#pragma unroll
        for (int k = 0; k < 8; ++k) acc[k] += p0 * (float)x0[k];
    }
    // combine the two halves
    dh += __shfl_xor(dh, 32);
#pragma unroll
    for (int k = 0; k < 8; ++k) acc[k] += __shfl_xor(acc[k], 32);
    float invh = 1.f / (dh + 1e-12f);
    // lane l (sub=0) writes dims [8l, 8l+4); lane l+32 writes [8l+4, 8l+8)
    float a0 = sub ? acc[4] : acc[0];
    float a1 = sub ? acc[5] : acc[1];
    float a2 = sub ? acc[6] : acc[2];
    float a3 = sub ? acc[7] : acc[3];
    int doff = l * 8 + sub * 4;
    float4 b = *(const float4*)&bias[doff];
    float4 o4;
    o4.x = a0 * invh + b.x;
    o4.y = a1 * invh + b.y;
    o4.z = a2 * invh + b.z;
    o4.w = a3 * invh + b.w;
    *(float4*)&out[(size_t)wid * HD + doff] = o4;
}

extern "C" void kernel_launch(void* const* d_in, const int* in_sizes, int n_in,
                              void* d_out, int out_size, void* d_ws, size_t ws_size,
                              hipStream_t stream) {
    const float* x        = (const float*)d_in[0];
    const int*   ei       = (const int*)d_in[1];
    const float* ea       = (const float*)d_in[2];
    const float* lin_W    = (const float*)d_in[3];
    const float* att_src  = (const float*)d_in[4];
    const float* att_dst  = (const float*)d_in[5];
    const float* lin_eW   = (const float*)d_in[6];
    const float* att_edge = (const float*)d_in[7];
    const float* bias     = (const float*)d_in[8];
    float* out = (float*)d_out;

    int n  = in_sizes[0] / IN_DIM;     // 20000
    int E  = in_sizes[2] / EDGE_DIM;   // 320000
    int EP = E + n;

    char* p = (char*)d_ws;
    auto alloc = [&](size_t bytes) {
        char* r = p;
        p += (bytes + 255) & ~(size_t)255;
        return r;
    };
    _Float16* xph   = (_Float16*)alloc((size_t)n * HD * 2);
    _Float16* Whr   = (_Float16*)alloc((size_t)HD * IN_DIM * 2);
    float* s_src    = (float*)alloc((size_t)n * 4 * 4);
    float* s_dst    = (float*)alloc((size_t)n * 4 * 4);
    int4*  rec      = (int4*)alloc((size_t)EP * 16);
    float* weff     = (float*)alloc(128 * 4);
    int*   deg      = (int*)alloc((size_t)(n + 4) * 4);
    int*   rowptr   = (int*)alloc((size_t)(n + 1) * 4);
    int*   perm     = (int*)alloc((size_t)E * 4);

    int n4 = (n + 3) & ~3;
    int ZV = (n4 + 1023) / 1024;
    int histv = (E + 1023) / 1024;
    int projv = (n + 31) / 32;

    k_pre<<<1 + WCVT_VBS + ZV, NTHR, 0, stream>>>(lin_eW, att_edge, lin_W, weff, Whr,
                                                  deg, n4);
    k_mid<<<histv + projv, NTHR, 0, stream>>>(ei, x, Whr, att_src, att_dst, xph,
                                              s_src, s_dst, deg, perm, histv, E, n);
    scan_kernel<<<1, SCAN_T, 0, stream>>>(deg, rowptr, n);
    edge_kernel<<<(EP + NTHR - 1) / NTHR, NTHR, 0, stream>>>(ei, ea, s_src, s_dst, weff,
                                                             rowptr, perm, rec, E, n);
    agg_kernel<<<(n + 3) / 4, NTHR, 0, stream>>>(rowptr, rec, xph, bias, out, n);
}